// Round 6
// baseline (498.638 us; speedup 1.0000x reference)
//
#include <hip/hip_runtime.h>
#include <math.h>

// Problem constants: B=4, N=256, D=512, H=8, HD=64, L=3, K_SPARSE=25, EPS=1e-5

// ---------------------------------------------------------------------------
// GEMM v3 (f32): C[M,N] = act(A[M,K] @ W[K,N] + bias). TM=32, thread owns
// 2 rows x 4 cols, vectorized LDS fragment reads.
// flags: 1 = relu, 2 = pool (pair-average rows, C gets M/2 rows)
// wmode: 0 none; 1 = fuse3; 2 = we1-split
// ---------------------------------------------------------------------------
template <int TM, typename ACC>
__global__ __launch_bounds__(256) void gemm_v3(
    const float* __restrict__ A, const float* __restrict__ W,
    const float* __restrict__ bias, float* __restrict__ C,
    int M, int N, int K, int flags, int wmode)
{
    constexpr int RT = TM / 16;
    constexpr int PAD = 4;
    __shared__ ACC As[16][TM + PAD];
    __shared__ ACC Ws[16][64 + PAD];

    const int tid = threadIdx.x;
    const int tx = tid & 15, ty = tid >> 4;
    const int bm = blockIdx.y * TM, bn = blockIdx.x * 64;

    const float* Wp = W;
    const float* bp = bias;
    int wn = N, wcol = bn;
    if (wmode == 1) {
        int seg = (bm >= 1536) ? 2 : (bm >= 1024) ? 1 : 0;
        Wp += (size_t)seg * 262144;
    } else if (wmode == 2) {
        if (bn >= 512) Wp += 262144; else bp = nullptr;
        wn = 512; wcol = bn & 511;
    }

    const int ar = tid >> 3, ac = (tid & 7) << 1;
    const int wr = tid >> 4;
    const int wc = (tid & 15) << 2;

    const float* Aptr = A + (size_t)(bm + ar) * K + ac;
    const float* Wptr = Wp + (size_t)wr * wn + wcol + wc;

    ACC acc[RT][4] = {};
    float ra[2], rw[4];

    {   // initial prefetch (k0 = 0)
        float2 v = *(const float2*)Aptr; ra[0] = v.x; ra[1] = v.y;
        float4 w = *(const float4*)Wptr;
        rw[0]=w.x; rw[1]=w.y; rw[2]=w.z; rw[3]=w.w;
    }

    for (int k0 = 0; k0 < K; k0 += 16) {
        if (k0) __syncthreads();
        As[ac + 0][ar] = (ACC)ra[0];
        As[ac + 1][ar] = (ACC)ra[1];
        #pragma unroll
        for (int u = 0; u < 4; ++u) Ws[wr][wc + u] = (ACC)rw[u];
        __syncthreads();

        if (k0 + 16 < K) {
            float2 v = *(const float2*)(Aptr + k0 + 16); ra[0] = v.x; ra[1] = v.y;
            float4 w = *(const float4*)(Wptr + (size_t)(k0 + 16) * wn);
            rw[0]=w.x; rw[1]=w.y; rw[2]=w.z; rw[3]=w.w;
        }

        #pragma unroll
        for (int kk = 0; kk < 16; ++kk) {
            ACC a[RT], w[4];
            #pragma unroll
            for (int i = 0; i < RT; ++i) a[i] = As[kk][ty * RT + i];
            #pragma unroll
            for (int j = 0; j < 4; ++j) w[j] = Ws[kk][tx * 4 + j];
            #pragma unroll
            for (int i = 0; i < RT; ++i)
                #pragma unroll
                for (int j = 0; j < 4; ++j)
                    acc[i][j] += a[i] * w[j];
        }
    }

    #pragma unroll
    for (int j = 0; j < 4; ++j) {
        const int cn = bn + tx * 4 + j;
        const ACC bv = bp ? (ACC)bp[(wmode == 2) ? (cn & 511) : cn] : (ACC)0;
        if (flags & 2) {
            #pragma unroll
            for (int pi = 0; pi < RT / 2; ++pi) {
                ACC f0 = acc[2 * pi][j] + bv;
                ACC f1 = acc[2 * pi + 1][j] + bv;
                if (flags & 1) {
                    f0 = f0 > (ACC)0 ? f0 : (ACC)0;
                    f1 = f1 > (ACC)0 ? f1 : (ACC)0;
                }
                int prow = ((bm + ty * RT) >> 1) + pi;
                C[(size_t)prow * N + cn] = (float)((f0 + f1) * (ACC)0.5);
            }
        } else {
            #pragma unroll
            for (int i = 0; i < RT; ++i) {
                ACC f = acc[i][j] + bv;
                if (flags & 1) f = f > (ACC)0 ? f : (ACC)0;
                C[(size_t)(bm + ty * RT + i) * N + cn] = (float)f;
            }
        }
    }
}

// ---------------------------------------------------------------------------
// f64-accum GEMM, strided conflict-free fragment map. TM=32, TN=64.
// Thread owns rows bm+ty+{0,16}, cols bn+tx+{0,16,32,48}.
// A staged f32 (cvt on read); W staged f64 at strided cols (banks 2*tx).
// flags: 1 = relu. wmode: 0 none; 1 = fuse3; 2 = we1-split.
// ---------------------------------------------------------------------------
__global__ __launch_bounds__(256) void gemm_f64s(
    const float* __restrict__ A, const float* __restrict__ W,
    const float* __restrict__ bias, float* __restrict__ C,
    int M, int N, int K, int flags, int wmode)
{
    __shared__ float  Asf[16][36];
    __shared__ double Wsd[16][68];

    const int tid = threadIdx.x;
    const int tx = tid & 15, ty = tid >> 4;
    const int bm = blockIdx.y * 32, bn = blockIdx.x * 64;

    const float* Wp = W;
    const float* bp = bias;
    int wn = N, wcol = bn;
    if (wmode == 1) {
        int seg = (bm >= 1536) ? 2 : (bm >= 1024) ? 1 : 0;
        Wp += (size_t)seg * 262144;
    } else if (wmode == 2) {
        if (bn >= 512) Wp += 262144; else bp = nullptr;
        wn = 512; wcol = bn & 511;
    }

    const int ar = tid >> 3, ac = (tid & 7) << 1;      // A staging
    const int wr = tid >> 4, wcs = tid & 15;           // W staging (strided)

    const float* Aptr = A + (size_t)(bm + ar) * K + ac;
    const float* Wptr = Wp + (size_t)wr * wn + wcol + wcs;

    double acc[2][4] = {};
    float ra0, ra1, rw[4];

    {   // initial prefetch
        float2 v = *(const float2*)Aptr; ra0 = v.x; ra1 = v.y;
        #pragma unroll
        for (int u = 0; u < 4; ++u) rw[u] = Wptr[u * 16];
    }

    for (int k0 = 0; k0 < K; k0 += 16) {
        if (k0) __syncthreads();
        Asf[ac + 0][ar] = ra0;
        Asf[ac + 1][ar] = ra1;
        #pragma unroll
        for (int u = 0; u < 4; ++u) Wsd[wr][wcs + u * 16] = (double)rw[u];
        __syncthreads();

        if (k0 + 16 < K) {
            float2 v = *(const float2*)(Aptr + k0 + 16); ra0 = v.x; ra1 = v.y;
            const float* wp2 = Wptr + (size_t)(k0 + 16) * wn;
            #pragma unroll
            for (int u = 0; u < 4; ++u) rw[u] = wp2[u * 16];
        }

        #pragma unroll
        for (int kk = 0; kk < 16; ++kk) {
            const double a0 = (double)Asf[kk][ty];
            const double a1 = (double)Asf[kk][ty + 16];
            const double w0 = Wsd[kk][tx];
            const double w1 = Wsd[kk][tx + 16];
            const double w2 = Wsd[kk][tx + 32];
            const double w3 = Wsd[kk][tx + 48];
            acc[0][0] += a0 * w0; acc[0][1] += a0 * w1;
            acc[0][2] += a0 * w2; acc[0][3] += a0 * w3;
            acc[1][0] += a1 * w0; acc[1][1] += a1 * w1;
            acc[1][2] += a1 * w2; acc[1][3] += a1 * w3;
        }
    }

    #pragma unroll
    for (int j = 0; j < 4; ++j) {
        const int cn = bn + tx + j * 16;
        const double bv = bp ? (double)bp[(wmode == 2) ? (cn & 511) : cn] : 0.0;
        #pragma unroll
        for (int i = 0; i < 2; ++i) {
            double f = acc[i][j] + bv;
            if (flags & 1) f = f > 0.0 ? f : 0.0;
            C[(size_t)(bm + ty + i * 16) * N + cn] = (float)f;
        }
    }
}

// ---------------------------------------------------------------------------
// Fused MHA core: out[b,i,h*64+d] = softmax(QK^T * 0.125) V
// qkv layout [B][n][1536] (q | k | v). Block = (4 q-rows, h, b), 4 waves.
// ---------------------------------------------------------------------------
__global__ __launch_bounds__(256) void attn_fused(
    const float* __restrict__ qkv, float* __restrict__ out, int n)
{
    const int lane = threadIdx.x & 63;
    const int w    = threadIdx.x >> 6;
    const int h = blockIdx.y, b = blockIdx.z;
    const int qi = blockIdx.x * 4 + w;
    const int nt = n >> 6;
    const size_t base = (size_t)b * n * 1536;

    __shared__ float q_lds[4][64];
    __shared__ float kv_lds[64][65];
    __shared__ float p_lds[4][256];

    q_lds[w][lane] = qkv[base + (size_t)qi * 1536 + h * 64 + lane];

    float s[4];
    for (int t = 0; t < nt; ++t) {
        const int j0 = t * 64;
        __syncthreads();
        {
            int r = threadIdx.x >> 2;
            int q4 = threadIdx.x & 3;
            const float* src = qkv + base + (size_t)(j0 + r) * 1536 + 512 + h * 64;
            #pragma unroll
            for (int u = 0; u < 4; ++u) {
                int c = u * 4 + q4;
                float4 v = *(const float4*)(src + c * 4);
                kv_lds[r][c * 4 + 0] = v.x; kv_lds[r][c * 4 + 1] = v.y;
                kv_lds[r][c * 4 + 2] = v.z; kv_lds[r][c * 4 + 3] = v.w;
            }
        }
        __syncthreads();
        float a0 = 0.f, a1 = 0.f, a2 = 0.f, a3 = 0.f;
        #pragma unroll
        for (int d = 0; d < 64; d += 4) {
            a0 += q_lds[w][d + 0] * kv_lds[lane][d + 0];
            a1 += q_lds[w][d + 1] * kv_lds[lane][d + 1];
            a2 += q_lds[w][d + 2] * kv_lds[lane][d + 2];
            a3 += q_lds[w][d + 3] * kv_lds[lane][d + 3];
        }
        s[t] = ((a0 + a1) + (a2 + a3)) * 0.125f;
    }

    float m = s[0];
    for (int t = 1; t < nt; ++t) m = fmaxf(m, s[t]);
    #pragma unroll
    for (int off = 32; off; off >>= 1) m = fmaxf(m, __shfl_xor(m, off));
    float p[4];
    double sum = 0.0;
    for (int t = 0; t < nt; ++t) { p[t] = expf(s[t] - m); sum += (double)p[t]; }
    #pragma unroll
    for (int off = 32; off; off >>= 1) sum += __shfl_xor(sum, off);
    const double inv = 1.0 / sum;
    for (int t = 0; t < nt; ++t) p_lds[w][t * 64 + lane] = p[t];

    float ac0 = 0.f, ac1 = 0.f, ac2 = 0.f, ac3 = 0.f;
    for (int t = 0; t < nt; ++t) {
        const int j0 = t * 64;
        __syncthreads();
        {
            int r = threadIdx.x >> 2;
            int q4 = threadIdx.x & 3;
            const float* src = qkv + base + (size_t)(j0 + r) * 1536 + 1024 + h * 64;
            #pragma unroll
            for (int u = 0; u < 4; ++u) {
                int c = u * 4 + q4;
                float4 v = *(const float4*)(src + c * 4);
                kv_lds[r][c * 4 + 0] = v.x; kv_lds[r][c * 4 + 1] = v.y;
                kv_lds[r][c * 4 + 2] = v.z; kv_lds[r][c * 4 + 3] = v.w;
            }
        }
        __syncthreads();
        #pragma unroll
        for (int jl = 0; jl < 64; jl += 4) {
            ac0 = fmaf(p_lds[w][j0 + jl + 0], kv_lds[jl + 0][lane], ac0);
            ac1 = fmaf(p_lds[w][j0 + jl + 1], kv_lds[jl + 1][lane], ac1);
            ac2 = fmaf(p_lds[w][j0 + jl + 2], kv_lds[jl + 2][lane], ac2);
            ac3 = fmaf(p_lds[w][j0 + jl + 3], kv_lds[jl + 3][lane], ac3);
        }
    }
    float acc = (ac0 + ac1) + (ac2 + ac3);
    out[((size_t)(b * n + qi)) * 512 + h * 64 + lane] = (float)((double)acc * inv);
}

// ---------------------------------------------------------------------------
// Fused 3-way add + bias + relu + LayerNorm. y = [y0(1024r) | y1(512r) | y2(256r)]
// ---------------------------------------------------------------------------
__global__ __launch_bounds__(64) void ln3_kernel(
    const float* __restrict__ y, const float* __restrict__ bf,
    const float* __restrict__ g, const float* __restrict__ bta,
    float* __restrict__ out)
{
    const int r = blockIdx.x, lane = threadIdx.x;
    const int b = r >> 8, i = r & 255;
    const float* y0 = y + (size_t)r * 512;
    const float* y1 = y + (size_t)(1024 + b * 128 + (i >> 1)) * 512;
    const float* y2 = y + (size_t)(1536 + b * 64 + (i >> 2)) * 512;
    double v[8];
    double sum = 0.0;
    #pragma unroll
    for (int t = 0; t < 8; ++t) {
        int d = t * 64 + lane;
        double s = (double)y0[d] + (double)y1[d] + (double)y2[d] + (double)bf[d];
        s = s > 0.0 ? s : 0.0;
        v[t] = s; sum += s;
    }
    #pragma unroll
    for (int off = 32; off; off >>= 1) sum += __shfl_xor(sum, off);
    const double mean = sum * (1.0 / 512.0);
    double ss = 0.0;
    #pragma unroll
    for (int t = 0; t < 8; ++t) { double d = v[t] - mean; ss += d * d; }
    #pragma unroll
    for (int off = 32; off; off >>= 1) ss += __shfl_xor(ss, off);
    const double rstd = 1.0 / sqrt(ss * (1.0 / 512.0) + 1e-5);
    #pragma unroll
    for (int t = 0; t < 8; ++t) {
        int d = t * 64 + lane;
        out[(size_t)r * 512 + d] =
            (float)((v[t] - mean) * rstd * (double)g[d] + (double)bta[d]);
    }
}

// ---------------------------------------------------------------------------
// Edge scores v3 (GEMM-shaped): z[i,j] = sum_d relu(hi[i,d]+hj[j,d]) * w2[d]
// S = sigmoid(z + be2), diag 0. hibjb[1024][1024]: cols 0:512 hi, 512:1024 hj.
// ---------------------------------------------------------------------------
__global__ __launch_bounds__(256) void scores_v3(
    const float* __restrict__ hibjb, const float* __restrict__ We2,
    const float* __restrict__ be2, float* __restrict__ S)
{
    __shared__ float Hi[16][36];
    __shared__ float Hj[16][36];
    __shared__ float W2s[512];
    const int b = blockIdx.z;
    const int i0 = blockIdx.y * 32, j0 = blockIdx.x * 32;
    const int tid = threadIdx.x;
    const int tx = tid & 15, ty = tid >> 4;

    for (int t = tid; t < 512; t += 256) W2s[t] = We2[t];

    const int sr = tid >> 3, sc = (tid & 7) << 1;
    const float* hiptr = hibjb + (size_t)(b * 256 + i0 + sr) * 1024 + sc;
    const float* hjptr = hibjb + (size_t)(b * 256 + j0 + sr) * 1024 + 512 + sc;

    double a00 = 0.0, a01 = 0.0, a10 = 0.0, a11 = 0.0;
    for (int k0 = 0; k0 < 512; k0 += 16) {
        __syncthreads();
        float2 hv = *(const float2*)(hiptr + k0);
        float2 jv = *(const float2*)(hjptr + k0);
        Hi[sc + 0][sr] = hv.x; Hi[sc + 1][sr] = hv.y;
        Hj[sc + 0][sr] = jv.x; Hj[sc + 1][sr] = jv.y;
        __syncthreads();
        #pragma unroll
        for (int kk = 0; kk < 16; ++kk) {
            const double wv = (double)W2s[k0 + kk];
            const float hi0 = Hi[kk][ty * 2 + 0], hi1 = Hi[kk][ty * 2 + 1];
            const float hj0 = Hj[kk][tx * 2 + 0], hj1 = Hj[kk][tx * 2 + 1];
            a00 += (double)fmaxf(hi0 + hj0, 0.f) * wv;
            a01 += (double)fmaxf(hi0 + hj1, 0.f) * wv;
            a10 += (double)fmaxf(hi1 + hj0, 0.f) * wv;
            a11 += (double)fmaxf(hi1 + hj1, 0.f) * wv;
        }
    }
    const double bb = (double)be2[0];
    const int gi0 = i0 + ty * 2, gj0 = j0 + tx * 2;
    double zz[2][2] = {{a00, a01}, {a10, a11}};
    #pragma unroll
    for (int ii = 0; ii < 2; ++ii)
        #pragma unroll
        for (int jj = 0; jj < 2; ++jj) {
            double z = zz[ii][jj] + bb;
            float sc_ = (float)(1.0 / (1.0 + exp(-z)));
            if (gi0 + ii == gj0 + jj) sc_ = 0.f;
            S[(size_t)(b * 256 + gi0 + ii) * 256 + gj0 + jj] = sc_;
        }
}

// ---------------------------------------------------------------------------
// Top-k(25) one-hot per row of 256 (ties -> lower index, like lax.top_k).
// ---------------------------------------------------------------------------
__global__ __launch_bounds__(64) void topk_kernel(
    const float* __restrict__ S, float* __restrict__ out)
{
    const int row = blockIdx.x;
    const int lane = threadIdx.x;
    float v[4]; int sel[4] = {0, 0, 0, 0};
    #pragma unroll
    for (int t = 0; t < 4; ++t) v[t] = S[(size_t)row * 256 + t * 64 + lane];
    for (int it = 0; it < 25; ++it) {
        float bv = v[0]; int bi = lane;
        #pragma unroll
        for (int t = 1; t < 4; ++t) {
            int idx = t * 64 + lane;
            if (v[t] > bv) { bv = v[t]; bi = idx; }
        }
        #pragma unroll
        for (int off = 32; off; off >>= 1) {
            float ov = __shfl_xor(bv, off);
            int   oi = __shfl_xor(bi, off);
            if (ov > bv || (ov == bv && oi < bi)) { bv = ov; bi = oi; }
        }
        if ((bi & 63) == lane) { int t = bi >> 6; sel[t] = 1; v[t] = -INFINITY; }
    }
    #pragma unroll
    for (int t = 0; t < 4; ++t)
        out[(size_t)row * 256 + t * 64 + lane] = (float)sel[t];
}

// ---------------------------------------------------------------------------
extern "C" void kernel_launch(void* const* d_in, const int* in_sizes, int n_in,
                              void* d_out, int out_size, void* d_ws, size_t ws_size,
                              hipStream_t stream)
{
    const float* x      = (const float*)d_in[0];
    const float* Wqkv   = (const float*)d_in[2];
    const float* bqkv   = (const float*)d_in[3];
    const float* Wo     = (const float*)d_in[4];
    const float* bo     = (const float*)d_in[5];
    const float* Wp1    = (const float*)d_in[6];
    const float* bp1    = (const float*)d_in[7];
    const float* Wp2    = (const float*)d_in[8];
    const float* bp2    = (const float*)d_in[9];
    const float* Wfuse  = (const float*)d_in[10];
    const float* bfuse  = (const float*)d_in[11];
    const float* ln_g   = (const float*)d_in[12];
    const float* ln_b   = (const float*)d_in[13];
    const float* We1    = (const float*)d_in[14];
    const float* be1    = (const float*)d_in[15];
    const float* We2    = (const float*)d_in[16];
    const float* be2    = (const float*)d_in[17];
    const float* Ws_qkv = (const float*)d_in[18];
    const float* bs_qkv = (const float*)d_in[19];
    const float* Ws_o   = (const float*)d_in[20];
    const float* bs_o   = (const float*)d_in[21];

    float* out_att    = (float*)d_out;               // 4*256*512
    float* out_sparse = out_att + 4 * 256 * 512;     // 4*256*256

    // workspace layout (floats)
    float* ws    = (float*)d_ws;
    float* qkvb  = ws;                    // 1,572,864 (also y-buffer for fuse3)
    float* attnb = qkvb + 1572864;        //   524,288
    float* lvls  = attnb + 524288;        //   917,504 (lvl0 | lvl1 | lvl2)
    float* poolb = lvls + 917504;         //   131,072
    float* curb  = poolb + 131072;        //   262,144
    float* hier  = curb + 262144;         //   524,288
    float* hibjb = hier + 524288;         // 1,048,576  [1024][1024] (hi | hj)
    float* scb   = hibjb + 1048576;       //   262,144

    float* lvl0 = lvls;
    float* lvl1 = lvls + 1024 * 512;
    float* lvl2 = lvls + 1536 * 512;

    auto G32 = [&](const float* A, const float* W, const float* bias, float* C,
                   int M, int N, int K, int flags, int wmode) {
        gemm_v3<32, float><<<dim3(N / 64, M / 32), 256, 0, stream>>>(
            A, W, bias, C, M, N, K, flags, wmode);
    };
    auto G64d = [&](const float* A, const float* W, const float* bias, float* C,
                    int M, int N, int K, int flags, int wmode) {
        gemm_f64s<<<dim3(N / 64, M / 32), 256, 0, stream>>>(
            A, W, bias, C, M, N, K, flags, wmode);
    };

    // ---- Level 0 (n=256) ----
    G32(x, Wqkv, bqkv, qkvb, 1024, 1536, 512, 0, 0);
    attn_fused<<<dim3(64, 8, 4), 256, 0, stream>>>(qkvb, attnb, 256);
    G32(attnb, Wo, bo, lvl0, 1024, 512, 512, 0, 0);
    G32(lvl0, Wp1, bp1, poolb, 1024, 256, 512, 3, 0);     // relu+pool -> [512][256]
    G32(poolb, Wp2, bp2, curb, 512, 512, 256, 0, 0);

    // ---- Level 1 (n=128) ----
    G32(curb, Wqkv + 512 * 1536, bqkv + 1536, qkvb, 512, 1536, 512, 0, 0);
    attn_fused<<<dim3(32, 8, 4), 256, 0, stream>>>(qkvb, attnb, 128);
    G32(attnb, Wo + 512 * 512, bo + 512, lvl1, 512, 512, 512, 0, 0);
    G32(lvl1, Wp1 + 512 * 256, bp1 + 256, poolb, 512, 256, 512, 3, 0);  // -> [256][256]
    G32(poolb, Wp2 + 256 * 512, bp2 + 512, curb, 256, 512, 256, 0, 0);

    // ---- Level 2 (n=64) ----
    G32(curb, Wqkv + 2 * 512 * 1536, bqkv + 2 * 1536, qkvb, 256, 1536, 512, 0, 0);
    attn_fused<<<dim3(16, 8, 4), 256, 0, stream>>>(qkvb, attnb, 64);
    G32(attnb, Wo + 2 * 512 * 512, bo + 2 * 512, lvl2, 256, 512, 512, 0, 0);

    // ---- Fuse (batched partial GEMM, f64) + LN ----
    G64d(lvls, Wfuse, nullptr, qkvb, 1792, 512, 512, 0, 1);   // y -> qkvb
    ln3_kernel<<<1024, 64, 0, stream>>>(qkvb, bfuse, ln_g, ln_b, hier);

    // ---- Sparse edge scoring + top-k (f64 near the decision) ----
    G64d(hier, We1, be1, hibjb, 1024, 1024, 512, 0, 2);       // [hi | hj]
    scores_v3<<<dim3(8, 8, 4), 256, 0, stream>>>(hibjb, We2, be2, scb);
    topk_kernel<<<1024, 64, 0, stream>>>(scb, out_sparse);

    // ---- Final MHA on hier (feeds only output 0, bf16 tol) ----
    G32(hier, Ws_qkv, bs_qkv, qkvb, 1024, 1536, 512, 0, 0);
    attn_fused<<<dim3(64, 8, 4), 256, 0, stream>>>(qkvb, attnb, 256);
    G32(attnb, Ws_o, bs_o, out_att, 1024, 512, 512, 0, 0);
}

// Round 7
// 457.559 us; speedup vs baseline: 1.0898x; 1.0898x over previous
//
#include <hip/hip_runtime.h>
#include <math.h>

// Problem constants: B=4, N=256, D=512, H=8, HD=64, L=3, K_SPARSE=25, EPS=1e-5

// ---------------------------------------------------------------------------
// GEMM v3 (f32): C[M,N] = act(A[M,K] @ W[K,N] + bias). TM=32, thread owns
// 2 rows x 4 cols, vectorized LDS fragment reads.
// flags: 1 = relu, 2 = pool (pair-average rows, C gets M/2 rows)
// wmode: 0 none; 1 = fuse3 (W += seg(bm)*512*512, seg rows at 1024/1536);
//        2 = we1-split (W stride 512; bn>=512 -> W += 512*512, bias on; else no bias)
// ---------------------------------------------------------------------------
template <int TM, typename ACC>
__global__ __launch_bounds__(256) void gemm_v3(
    const float* __restrict__ A, const float* __restrict__ W,
    const float* __restrict__ bias, float* __restrict__ C,
    int M, int N, int K, int flags, int wmode)
{
    constexpr int RT = TM / 16;
    constexpr int PAD = 4;
    __shared__ ACC As[16][TM + PAD];
    __shared__ ACC Ws[16][64 + PAD];

    const int tid = threadIdx.x;
    const int tx = tid & 15, ty = tid >> 4;
    const int bm = blockIdx.y * TM, bn = blockIdx.x * 64;

    const float* Wp = W;
    const float* bp = bias;
    int wn = N, wcol = bn;
    if (wmode == 1) {
        int seg = (bm >= 1536) ? 2 : (bm >= 1024) ? 1 : 0;
        Wp += (size_t)seg * 262144;
    } else if (wmode == 2) {
        if (bn >= 512) Wp += 262144; else bp = nullptr;
        wn = 512; wcol = bn & 511;
    }

    const int ar = tid >> 3, ac = (tid & 7) << 1;
    const int wr = tid >> 4;
    const int wc = (tid & 15) << 2;

    const float* Aptr = A + (size_t)(bm + ar) * K + ac;
    const float* Wptr = Wp + (size_t)wr * wn + wcol + wc;

    ACC acc[RT][4] = {};
    float ra[2], rw[4];

    {   // initial prefetch (k0 = 0)
        float2 v = *(const float2*)Aptr; ra[0] = v.x; ra[1] = v.y;
        float4 w = *(const float4*)Wptr;
        rw[0]=w.x; rw[1]=w.y; rw[2]=w.z; rw[3]=w.w;
    }

    for (int k0 = 0; k0 < K; k0 += 16) {
        if (k0) __syncthreads();
        As[ac + 0][ar] = (ACC)ra[0];
        As[ac + 1][ar] = (ACC)ra[1];
        #pragma unroll
        for (int u = 0; u < 4; ++u) Ws[wr][wc + u] = (ACC)rw[u];
        __syncthreads();

        if (k0 + 16 < K) {
            float2 v = *(const float2*)(Aptr + k0 + 16); ra[0] = v.x; ra[1] = v.y;
            float4 w = *(const float4*)(Wptr + (size_t)(k0 + 16) * wn);
            rw[0]=w.x; rw[1]=w.y; rw[2]=w.z; rw[3]=w.w;
        }

        #pragma unroll
        for (int kk = 0; kk < 16; ++kk) {
            ACC a[RT], w[4];
            #pragma unroll
            for (int i = 0; i < RT; ++i) a[i] = As[kk][ty * RT + i];
            #pragma unroll
            for (int j = 0; j < 4; ++j) w[j] = Ws[kk][tx * 4 + j];
            #pragma unroll
            for (int i = 0; i < RT; ++i)
                #pragma unroll
                for (int j = 0; j < 4; ++j)
                    acc[i][j] += a[i] * w[j];
        }
    }

    #pragma unroll
    for (int j = 0; j < 4; ++j) {
        const int cn = bn + tx * 4 + j;
        const ACC bv = bp ? (ACC)bp[(wmode == 2) ? (cn & 511) : cn] : (ACC)0;
        if (flags & 2) {
            #pragma unroll
            for (int pi = 0; pi < RT / 2; ++pi) {
                ACC f0 = acc[2 * pi][j] + bv;
                ACC f1 = acc[2 * pi + 1][j] + bv;
                if (flags & 1) {
                    f0 = f0 > (ACC)0 ? f0 : (ACC)0;
                    f1 = f1 > (ACC)0 ? f1 : (ACC)0;
                }
                int prow = ((bm + ty * RT) >> 1) + pi;
                C[(size_t)prow * N + cn] = (float)((f0 + f1) * (ACC)0.5);
            }
        } else {
            #pragma unroll
            for (int i = 0; i < RT; ++i) {
                ACC f = acc[i][j] + bv;
                if (flags & 1) f = f > (ACC)0 ? f : (ACC)0;
                C[(size_t)(bm + ty * RT + i) * N + cn] = (float)f;
            }
        }
    }
}

// ---------------------------------------------------------------------------
// Fused MHA core: out[b,i,h*64+d] = softmax(QK^T * 0.125) V
// qkv layout [B][n][1536] (q | k | v). Block = (4 q-rows, h, b), 4 waves.
// ---------------------------------------------------------------------------
__global__ __launch_bounds__(256) void attn_fused(
    const float* __restrict__ qkv, float* __restrict__ out, int n)
{
    const int lane = threadIdx.x & 63;
    const int w    = threadIdx.x >> 6;
    const int h = blockIdx.y, b = blockIdx.z;
    const int qi = blockIdx.x * 4 + w;
    const int nt = n >> 6;
    const size_t base = (size_t)b * n * 1536;

    __shared__ float q_lds[4][64];
    __shared__ float kv_lds[64][65];
    __shared__ float p_lds[4][256];

    q_lds[w][lane] = qkv[base + (size_t)qi * 1536 + h * 64 + lane];

    float s[4];
    for (int t = 0; t < nt; ++t) {
        const int j0 = t * 64;
        __syncthreads();
        {
            int r = threadIdx.x >> 2;
            int q4 = threadIdx.x & 3;
            const float* src = qkv + base + (size_t)(j0 + r) * 1536 + 512 + h * 64;
            #pragma unroll
            for (int u = 0; u < 4; ++u) {
                int c = u * 4 + q4;
                float4 v = *(const float4*)(src + c * 4);
                kv_lds[r][c * 4 + 0] = v.x; kv_lds[r][c * 4 + 1] = v.y;
                kv_lds[r][c * 4 + 2] = v.z; kv_lds[r][c * 4 + 3] = v.w;
            }
        }
        __syncthreads();
        float a0 = 0.f, a1 = 0.f, a2 = 0.f, a3 = 0.f;
        #pragma unroll
        for (int d = 0; d < 64; d += 4) {
            a0 += q_lds[w][d + 0] * kv_lds[lane][d + 0];
            a1 += q_lds[w][d + 1] * kv_lds[lane][d + 1];
            a2 += q_lds[w][d + 2] * kv_lds[lane][d + 2];
            a3 += q_lds[w][d + 3] * kv_lds[lane][d + 3];
        }
        s[t] = ((a0 + a1) + (a2 + a3)) * 0.125f;
    }

    float m = s[0];
    for (int t = 1; t < nt; ++t) m = fmaxf(m, s[t]);
    #pragma unroll
    for (int off = 32; off; off >>= 1) m = fmaxf(m, __shfl_xor(m, off));
    float p[4];
    double sum = 0.0;
    for (int t = 0; t < nt; ++t) { p[t] = expf(s[t] - m); sum += (double)p[t]; }
    #pragma unroll
    for (int off = 32; off; off >>= 1) sum += __shfl_xor(sum, off);
    const double inv = 1.0 / sum;
    for (int t = 0; t < nt; ++t) p_lds[w][t * 64 + lane] = p[t];

    float ac0 = 0.f, ac1 = 0.f, ac2 = 0.f, ac3 = 0.f;
    for (int t = 0; t < nt; ++t) {
        const int j0 = t * 64;
        __syncthreads();
        {
            int r = threadIdx.x >> 2;
            int q4 = threadIdx.x & 3;
            const float* src = qkv + base + (size_t)(j0 + r) * 1536 + 1024 + h * 64;
            #pragma unroll
            for (int u = 0; u < 4; ++u) {
                int c = u * 4 + q4;
                float4 v = *(const float4*)(src + c * 4);
                kv_lds[r][c * 4 + 0] = v.x; kv_lds[r][c * 4 + 1] = v.y;
                kv_lds[r][c * 4 + 2] = v.z; kv_lds[r][c * 4 + 3] = v.w;
            }
        }
        __syncthreads();
        #pragma unroll
        for (int jl = 0; jl < 64; jl += 4) {
            ac0 = fmaf(p_lds[w][j0 + jl + 0], kv_lds[jl + 0][lane], ac0);
            ac1 = fmaf(p_lds[w][j0 + jl + 1], kv_lds[jl + 1][lane], ac1);
            ac2 = fmaf(p_lds[w][j0 + jl + 2], kv_lds[jl + 2][lane], ac2);
            ac3 = fmaf(p_lds[w][j0 + jl + 3], kv_lds[jl + 3][lane], ac3);
        }
    }
    float acc = (ac0 + ac1) + (ac2 + ac3);
    out[((size_t)(b * n + qi)) * 512 + h * 64 + lane] = (float)((double)acc * inv);
}

// ---------------------------------------------------------------------------
// Fused 3-way add + bias + relu + LayerNorm. y = [y0(1024r) | y1(512r) | y2(256r)]
// ---------------------------------------------------------------------------
__global__ __launch_bounds__(64) void ln3_kernel(
    const float* __restrict__ y, const float* __restrict__ bf,
    const float* __restrict__ g, const float* __restrict__ bta,
    float* __restrict__ out)
{
    const int r = blockIdx.x, lane = threadIdx.x;
    const int b = r >> 8, i = r & 255;
    const float* y0 = y + (size_t)r * 512;
    const float* y1 = y + (size_t)(1024 + b * 128 + (i >> 1)) * 512;
    const float* y2 = y + (size_t)(1536 + b * 64 + (i >> 2)) * 512;
    double v[8];
    double sum = 0.0;
    #pragma unroll
    for (int t = 0; t < 8; ++t) {
        int d = t * 64 + lane;
        double s = (double)y0[d] + (double)y1[d] + (double)y2[d] + (double)bf[d];
        s = s > 0.0 ? s : 0.0;
        v[t] = s; sum += s;
    }
    #pragma unroll
    for (int off = 32; off; off >>= 1) sum += __shfl_xor(sum, off);
    const double mean = sum * (1.0 / 512.0);
    double ss = 0.0;
    #pragma unroll
    for (int t = 0; t < 8; ++t) { double d = v[t] - mean; ss += d * d; }
    #pragma unroll
    for (int off = 32; off; off >>= 1) ss += __shfl_xor(ss, off);
    const double rstd = 1.0 / sqrt(ss * (1.0 / 512.0) + 1e-5);
    #pragma unroll
    for (int t = 0; t < 8; ++t) {
        int d = t * 64 + lane;
        out[(size_t)r * 512 + d] =
            (float)((v[t] - mean) * rstd * (double)g[d] + (double)bta[d]);
    }
}

// ---------------------------------------------------------------------------
// Edge scores v3 (GEMM-shaped): z[i,j] = sum_d relu(hi[i,d]+hj[j,d]) * w2[d]
// S = sigmoid(z + be2), diag 0. hibjb[1024][1024]: cols 0:512 hi, 512:1024 hj.
// f64 accumulation (closest to the top-k decision).
// ---------------------------------------------------------------------------
__global__ __launch_bounds__(256) void scores_v3(
    const float* __restrict__ hibjb, const float* __restrict__ We2,
    const float* __restrict__ be2, float* __restrict__ S)
{
    __shared__ float Hi[16][36];
    __shared__ float Hj[16][36];
    __shared__ float W2s[512];
    const int b = blockIdx.z;
    const int i0 = blockIdx.y * 32, j0 = blockIdx.x * 32;
    const int tid = threadIdx.x;
    const int tx = tid & 15, ty = tid >> 4;

    for (int t = tid; t < 512; t += 256) W2s[t] = We2[t];

    const int sr = tid >> 3, sc = (tid & 7) << 1;
    const float* hiptr = hibjb + (size_t)(b * 256 + i0 + sr) * 1024 + sc;
    const float* hjptr = hibjb + (size_t)(b * 256 + j0 + sr) * 1024 + 512 + sc;

    double a00 = 0.0, a01 = 0.0, a10 = 0.0, a11 = 0.0;
    for (int k0 = 0; k0 < 512; k0 += 16) {
        __syncthreads();
        float2 hv = *(const float2*)(hiptr + k0);
        float2 jv = *(const float2*)(hjptr + k0);
        Hi[sc + 0][sr] = hv.x; Hi[sc + 1][sr] = hv.y;
        Hj[sc + 0][sr] = jv.x; Hj[sc + 1][sr] = jv.y;
        __syncthreads();
        #pragma unroll
        for (int kk = 0; kk < 16; ++kk) {
            const double wv = (double)W2s[k0 + kk];
            const float hi0 = Hi[kk][ty * 2 + 0], hi1 = Hi[kk][ty * 2 + 1];
            const float hj0 = Hj[kk][tx * 2 + 0], hj1 = Hj[kk][tx * 2 + 1];
            a00 += (double)fmaxf(hi0 + hj0, 0.f) * wv;
            a01 += (double)fmaxf(hi0 + hj1, 0.f) * wv;
            a10 += (double)fmaxf(hi1 + hj0, 0.f) * wv;
            a11 += (double)fmaxf(hi1 + hj1, 0.f) * wv;
        }
    }
    const double bb = (double)be2[0];
    const int gi0 = i0 + ty * 2, gj0 = j0 + tx * 2;
    double zz[2][2] = {{a00, a01}, {a10, a11}};
    #pragma unroll
    for (int ii = 0; ii < 2; ++ii)
        #pragma unroll
        for (int jj = 0; jj < 2; ++jj) {
            double z = zz[ii][jj] + bb;
            float sc_ = (float)(1.0 / (1.0 + exp(-z)));
            if (gi0 + ii == gj0 + jj) sc_ = 0.f;
            S[(size_t)(b * 256 + gi0 + ii) * 256 + gj0 + jj] = sc_;
        }
}

// ---------------------------------------------------------------------------
// Top-k(25) one-hot per row of 256 (ties -> lower index, like lax.top_k).
// ---------------------------------------------------------------------------
__global__ __launch_bounds__(64) void topk_kernel(
    const float* __restrict__ S, float* __restrict__ out)
{
    const int row = blockIdx.x;
    const int lane = threadIdx.x;
    float v[4]; int sel[4] = {0, 0, 0, 0};
    #pragma unroll
    for (int t = 0; t < 4; ++t) v[t] = S[(size_t)row * 256 + t * 64 + lane];
    for (int it = 0; it < 25; ++it) {
        float bv = v[0]; int bi = lane;
        #pragma unroll
        for (int t = 1; t < 4; ++t) {
            int idx = t * 64 + lane;
            if (v[t] > bv) { bv = v[t]; bi = idx; }
        }
        #pragma unroll
        for (int off = 32; off; off >>= 1) {
            float ov = __shfl_xor(bv, off);
            int   oi = __shfl_xor(bi, off);
            if (ov > bv || (ov == bv && oi < bi)) { bv = ov; bi = oi; }
        }
        if ((bi & 63) == lane) { int t = bi >> 6; sel[t] = 1; v[t] = -INFINITY; }
    }
    #pragma unroll
    for (int t = 0; t < 4; ++t)
        out[(size_t)row * 256 + t * 64 + lane] = (float)sel[t];
}

// ---------------------------------------------------------------------------
extern "C" void kernel_launch(void* const* d_in, const int* in_sizes, int n_in,
                              void* d_out, int out_size, void* d_ws, size_t ws_size,
                              hipStream_t stream)
{
    const float* x      = (const float*)d_in[0];
    const float* Wqkv   = (const float*)d_in[2];
    const float* bqkv   = (const float*)d_in[3];
    const float* Wo     = (const float*)d_in[4];
    const float* bo     = (const float*)d_in[5];
    const float* Wp1    = (const float*)d_in[6];
    const float* bp1    = (const float*)d_in[7];
    const float* Wp2    = (const float*)d_in[8];
    const float* bp2    = (const float*)d_in[9];
    const float* Wfuse  = (const float*)d_in[10];
    const float* bfuse  = (const float*)d_in[11];
    const float* ln_g   = (const float*)d_in[12];
    const float* ln_b   = (const float*)d_in[13];
    const float* We1    = (const float*)d_in[14];
    const float* be1    = (const float*)d_in[15];
    const float* We2    = (const float*)d_in[16];
    const float* be2    = (const float*)d_in[17];
    const float* Ws_qkv = (const float*)d_in[18];
    const float* bs_qkv = (const float*)d_in[19];
    const float* Ws_o   = (const float*)d_in[20];
    const float* bs_o   = (const float*)d_in[21];

    float* out_att    = (float*)d_out;               // 4*256*512
    float* out_sparse = out_att + 4 * 256 * 512;     // 4*256*256

    // workspace layout (floats)
    float* ws    = (float*)d_ws;
    float* qkvb  = ws;                    // 1,572,864 (also y-buffer for fuse3)
    float* attnb = qkvb + 1572864;        //   524,288
    float* lvls  = attnb + 524288;        //   917,504 (lvl0 | lvl1 | lvl2)
    float* poolb = lvls + 917504;         //   131,072
    float* curb  = poolb + 131072;        //   262,144
    float* hier  = curb + 262144;         //   524,288
    float* hibjb = hier + 524288;         // 1,048,576  [1024][1024] (hi | hj)
    float* scb   = hibjb + 1048576;       //   262,144

    float* lvl0 = lvls;
    float* lvl1 = lvls + 1024 * 512;
    float* lvl2 = lvls + 1536 * 512;

    auto G32 = [&](const float* A, const float* W, const float* bias, float* C,
                   int M, int N, int K, int flags, int wmode) {
        gemm_v3<32, float><<<dim3(N / 64, M / 32), 256, 0, stream>>>(
            A, W, bias, C, M, N, K, flags, wmode);
    };

    // ---- Level 0 (n=256) ----
    G32(x, Wqkv, bqkv, qkvb, 1024, 1536, 512, 0, 0);
    attn_fused<<<dim3(64, 8, 4), 256, 0, stream>>>(qkvb, attnb, 256);
    G32(attnb, Wo, bo, lvl0, 1024, 512, 512, 0, 0);
    G32(lvl0, Wp1, bp1, poolb, 1024, 256, 512, 3, 0);     // relu+pool -> [512][256]
    G32(poolb, Wp2, bp2, curb, 512, 512, 256, 0, 0);

    // ---- Level 1 (n=128) ----
    G32(curb, Wqkv + 512 * 1536, bqkv + 1536, qkvb, 512, 1536, 512, 0, 0);
    attn_fused<<<dim3(32, 8, 4), 256, 0, stream>>>(qkvb, attnb, 128);
    G32(attnb, Wo + 512 * 512, bo + 512, lvl1, 512, 512, 512, 0, 0);
    G32(lvl1, Wp1 + 512 * 256, bp1 + 256, poolb, 512, 256, 512, 3, 0);  // -> [256][256]
    G32(poolb, Wp2 + 256 * 512, bp2 + 512, curb, 256, 512, 256, 0, 0);

    // ---- Level 2 (n=64) ----
    G32(curb, Wqkv + 2 * 512 * 1536, bqkv + 2 * 1536, qkvb, 256, 1536, 512, 0, 0);
    attn_fused<<<dim3(16, 8, 4), 256, 0, stream>>>(qkvb, attnb, 64);
    G32(attnb, Wo + 2 * 512 * 512, bo + 2 * 512, lvl2, 256, 512, 512, 0, 0);

    // ---- Fuse (batched partial GEMM) + LN ----
    G32(lvls, Wfuse, nullptr, qkvb, 1792, 512, 512, 0, 1);    // y -> qkvb
    ln3_kernel<<<1024, 64, 0, stream>>>(qkvb, bfuse, ln_g, ln_b, hier);

    // ---- Sparse edge scoring + top-k (scores dot stays f64) ----
    G32(hier, We1, be1, hibjb, 1024, 1024, 512, 0, 2);        // [hi | hj]
    scores_v3<<<dim3(8, 8, 4), 256, 0, stream>>>(hibjb, We2, be2, scb);
    topk_kernel<<<1024, 64, 0, stream>>>(scb, out_sparse);

    // ---- Final MHA on hier (feeds only output 0, bf16 tol) ----
    G32(hier, Ws_qkv, bs_qkv, qkvb, 1024, 1536, 512, 0, 0);
    attn_fused<<<dim3(64, 8, 4), 256, 0, stream>>>(qkvb, attnb, 256);
    G32(attnb, Ws_o, bs_o, out_att, 1024, 512, 512, 0, 0);
}

// Round 8
// 416.526 us; speedup vs baseline: 1.1971x; 1.0985x over previous
//
#include <hip/hip_runtime.h>
#include <math.h>

// Problem constants: B=4, N=256, D=512, H=8, HD=64, L=3, K_SPARSE=25, EPS=1e-5

// ---------------------------------------------------------------------------
// GEMM v3 (f32): C[M,N] = act(A[M,K] @ W[K,N] + bias). TM=32, thread owns
// 2 rows x 4 cols, vectorized LDS fragment reads.
// flags: 1 = relu, 2 = pool (pair-average rows, C gets M/2 rows)
// wmode: 0 none; 1 = fuse3 (W += seg(bm)*512*512, seg rows at 1024/1536);
//        2 = we1-split (W stride 512; bn>=512 -> W += 512*512, bias on; else no bias)
// ---------------------------------------------------------------------------
template <int TM, typename ACC>
__global__ __launch_bounds__(256) void gemm_v3(
    const float* __restrict__ A, const float* __restrict__ W,
    const float* __restrict__ bias, float* __restrict__ C,
    int M, int N, int K, int flags, int wmode)
{
    constexpr int RT = TM / 16;
    constexpr int PAD = 4;
    __shared__ ACC As[16][TM + PAD];
    __shared__ ACC Ws[16][64 + PAD];

    const int tid = threadIdx.x;
    const int tx = tid & 15, ty = tid >> 4;
    const int bm = blockIdx.y * TM, bn = blockIdx.x * 64;

    const float* Wp = W;
    const float* bp = bias;
    int wn = N, wcol = bn;
    if (wmode == 1) {
        int seg = (bm >= 1536) ? 2 : (bm >= 1024) ? 1 : 0;
        Wp += (size_t)seg * 262144;
    } else if (wmode == 2) {
        if (bn >= 512) Wp += 262144; else bp = nullptr;
        wn = 512; wcol = bn & 511;
    }

    const int ar = tid >> 3, ac = (tid & 7) << 1;
    const int wr = tid >> 4;
    const int wc = (tid & 15) << 2;

    const float* Aptr = A + (size_t)(bm + ar) * K + ac;
    const float* Wptr = Wp + (size_t)wr * wn + wcol + wc;

    ACC acc[RT][4] = {};
    float ra[2], rw[4];

    {   // initial prefetch (k0 = 0)
        float2 v = *(const float2*)Aptr; ra[0] = v.x; ra[1] = v.y;
        float4 w = *(const float4*)Wptr;
        rw[0]=w.x; rw[1]=w.y; rw[2]=w.z; rw[3]=w.w;
    }

    for (int k0 = 0; k0 < K; k0 += 16) {
        if (k0) __syncthreads();
        As[ac + 0][ar] = (ACC)ra[0];
        As[ac + 1][ar] = (ACC)ra[1];
        #pragma unroll
        for (int u = 0; u < 4; ++u) Ws[wr][wc + u] = (ACC)rw[u];
        __syncthreads();

        if (k0 + 16 < K) {
            float2 v = *(const float2*)(Aptr + k0 + 16); ra[0] = v.x; ra[1] = v.y;
            float4 w = *(const float4*)(Wptr + (size_t)(k0 + 16) * wn);
            rw[0]=w.x; rw[1]=w.y; rw[2]=w.z; rw[3]=w.w;
        }

        #pragma unroll
        for (int kk = 0; kk < 16; ++kk) {
            ACC a[RT], w[4];
            #pragma unroll
            for (int i = 0; i < RT; ++i) a[i] = As[kk][ty * RT + i];
            #pragma unroll
            for (int j = 0; j < 4; ++j) w[j] = Ws[kk][tx * 4 + j];
            #pragma unroll
            for (int i = 0; i < RT; ++i)
                #pragma unroll
                for (int j = 0; j < 4; ++j)
                    acc[i][j] += a[i] * w[j];
        }
    }

    #pragma unroll
    for (int j = 0; j < 4; ++j) {
        const int cn = bn + tx * 4 + j;
        const ACC bv = bp ? (ACC)bp[(wmode == 2) ? (cn & 511) : cn] : (ACC)0;
        if (flags & 2) {
            #pragma unroll
            for (int pi = 0; pi < RT / 2; ++pi) {
                ACC f0 = acc[2 * pi][j] + bv;
                ACC f1 = acc[2 * pi + 1][j] + bv;
                if (flags & 1) {
                    f0 = f0 > (ACC)0 ? f0 : (ACC)0;
                    f1 = f1 > (ACC)0 ? f1 : (ACC)0;
                }
                int prow = ((bm + ty * RT) >> 1) + pi;
                C[(size_t)prow * N + cn] = (float)((f0 + f1) * (ACC)0.5);
            }
        } else {
            #pragma unroll
            for (int i = 0; i < RT; ++i) {
                ACC f = acc[i][j] + bv;
                if (flags & 1) f = f > (ACC)0 ? f : (ACC)0;
                C[(size_t)(bm + ty * RT + i) * N + cn] = (float)f;
            }
        }
    }
}

// ---------------------------------------------------------------------------
// Fused MHA v2: out[b,i,h*64+d] = softmax(QK^T * 0.125) V
// qkv layout [B][n][1536] (q | k | v). Block = (16 q-rows, h, b), 4 waves;
// each wave owns 4 q-rows -> kv tile staged once per 16 rows, kv read once
// per 4 rows. NT = n/64 compile-time (all score/prob arrays reg-resident).
// ---------------------------------------------------------------------------
template <int NT>
__global__ __launch_bounds__(256) void attn_v2(
    const float* __restrict__ qkv, float* __restrict__ out, int n)
{
    const int lane = threadIdx.x & 63;
    const int w    = threadIdx.x >> 6;
    const int h = blockIdx.y, b = blockIdx.z;
    const int q0 = blockIdx.x * 16;
    const size_t base = (size_t)b * n * 1536;

    __shared__ float q_lds[16][64];
    __shared__ float kv_lds[64][65];
    __shared__ float p_lds[16][256];

    {   // load 16 q rows (1 float4 / thread)
        int r = threadIdx.x >> 4, c4 = (threadIdx.x & 15) << 2;
        float4 v = *(const float4*)(qkv + base + (size_t)(q0 + r) * 1536 + h * 64 + c4);
        q_lds[r][c4 + 0] = v.x; q_lds[r][c4 + 1] = v.y;
        q_lds[r][c4 + 2] = v.z; q_lds[r][c4 + 3] = v.w;
    }

    const int r0 = w * 4;                 // wave's first row within block
    const int sr = threadIdx.x >> 2;      // staging row
    const int sq = threadIdx.x & 3;       // staging quad

    float s[4][NT];

    // ---- QK^T ----
    #pragma unroll
    for (int t = 0; t < NT; ++t) {
        const int j0 = t * 64;
        __syncthreads();
        {   // stage K tile rows j0..j0+63
            const float* src = qkv + base + (size_t)(j0 + sr) * 1536 + 512 + h * 64;
            #pragma unroll
            for (int u = 0; u < 4; ++u) {
                int c = u * 4 + sq;
                float4 v = *(const float4*)(src + c * 4);
                kv_lds[sr][c * 4 + 0] = v.x; kv_lds[sr][c * 4 + 1] = v.y;
                kv_lds[sr][c * 4 + 2] = v.z; kv_lds[sr][c * 4 + 3] = v.w;
            }
        }
        __syncthreads();
        float c0 = 0.f, c1 = 0.f, c2 = 0.f, c3 = 0.f;
        #pragma unroll
        for (int d = 0; d < 64; ++d) {
            const float kvv = kv_lds[lane][d];
            c0 = fmaf(q_lds[r0 + 0][d], kvv, c0);
            c1 = fmaf(q_lds[r0 + 1][d], kvv, c1);
            c2 = fmaf(q_lds[r0 + 2][d], kvv, c2);
            c3 = fmaf(q_lds[r0 + 3][d], kvv, c3);
        }
        s[0][t] = c0 * 0.125f; s[1][t] = c1 * 0.125f;
        s[2][t] = c2 * 0.125f; s[3][t] = c3 * 0.125f;
    }

    // ---- softmax per row (register + wave reduce) ----
    double inv[4];
    #pragma unroll
    for (int qr = 0; qr < 4; ++qr) {
        float m = s[qr][0];
        #pragma unroll
        for (int t = 1; t < NT; ++t) m = fmaxf(m, s[qr][t]);
        #pragma unroll
        for (int off = 32; off; off >>= 1) m = fmaxf(m, __shfl_xor(m, off));
        double sum = 0.0;
        #pragma unroll
        for (int t = 0; t < NT; ++t) {
            float p = expf(s[qr][t] - m);
            p_lds[r0 + qr][t * 64 + lane] = p;
            sum += (double)p;
        }
        #pragma unroll
        for (int off = 32; off; off >>= 1) sum += __shfl_xor(sum, off);
        inv[qr] = 1.0 / sum;
    }

    // ---- PV (d = lane) ----
    float o0 = 0.f, o1 = 0.f, o2 = 0.f, o3 = 0.f;
    #pragma unroll
    for (int t = 0; t < NT; ++t) {
        const int j0 = t * 64;
        __syncthreads();
        {   // stage V tile
            const float* src = qkv + base + (size_t)(j0 + sr) * 1536 + 1024 + h * 64;
            #pragma unroll
            for (int u = 0; u < 4; ++u) {
                int c = u * 4 + sq;
                float4 v = *(const float4*)(src + c * 4);
                kv_lds[sr][c * 4 + 0] = v.x; kv_lds[sr][c * 4 + 1] = v.y;
                kv_lds[sr][c * 4 + 2] = v.z; kv_lds[sr][c * 4 + 3] = v.w;
            }
        }
        __syncthreads();
        #pragma unroll
        for (int jl = 0; jl < 64; ++jl) {
            const float vv = kv_lds[jl][lane];
            o0 = fmaf(p_lds[r0 + 0][t * 64 + jl], vv, o0);
            o1 = fmaf(p_lds[r0 + 1][t * 64 + jl], vv, o1);
            o2 = fmaf(p_lds[r0 + 2][t * 64 + jl], vv, o2);
            o3 = fmaf(p_lds[r0 + 3][t * 64 + jl], vv, o3);
        }
    }
    const size_t obase = ((size_t)(b * n + q0 + r0)) * 512 + h * 64 + lane;
    out[obase + 0 * 512] = (float)((double)o0 * inv[0]);
    out[obase + 1 * 512] = (float)((double)o1 * inv[1]);
    out[obase + 2 * 512] = (float)((double)o2 * inv[2]);
    out[obase + 3 * 512] = (float)((double)o3 * inv[3]);
}

// ---------------------------------------------------------------------------
// Fused 3-way add + bias + relu + LayerNorm. y = [y0(1024r) | y1(512r) | y2(256r)]
// ---------------------------------------------------------------------------
__global__ __launch_bounds__(64) void ln3_kernel(
    const float* __restrict__ y, const float* __restrict__ bf,
    const float* __restrict__ g, const float* __restrict__ bta,
    float* __restrict__ out)
{
    const int r = blockIdx.x, lane = threadIdx.x;
    const int b = r >> 8, i = r & 255;
    const float* y0 = y + (size_t)r * 512;
    const float* y1 = y + (size_t)(1024 + b * 128 + (i >> 1)) * 512;
    const float* y2 = y + (size_t)(1536 + b * 64 + (i >> 2)) * 512;
    double v[8];
    double sum = 0.0;
    #pragma unroll
    for (int t = 0; t < 8; ++t) {
        int d = t * 64 + lane;
        double s = (double)y0[d] + (double)y1[d] + (double)y2[d] + (double)bf[d];
        s = s > 0.0 ? s : 0.0;
        v[t] = s; sum += s;
    }
    #pragma unroll
    for (int off = 32; off; off >>= 1) sum += __shfl_xor(sum, off);
    const double mean = sum * (1.0 / 512.0);
    double ss = 0.0;
    #pragma unroll
    for (int t = 0; t < 8; ++t) { double d = v[t] - mean; ss += d * d; }
    #pragma unroll
    for (int off = 32; off; off >>= 1) ss += __shfl_xor(ss, off);
    const double rstd = 1.0 / sqrt(ss * (1.0 / 512.0) + 1e-5);
    #pragma unroll
    for (int t = 0; t < 8; ++t) {
        int d = t * 64 + lane;
        out[(size_t)r * 512 + d] =
            (float)((v[t] - mean) * rstd * (double)g[d] + (double)bta[d]);
    }
}

// ---------------------------------------------------------------------------
// Edge scores v3 (GEMM-shaped): z[i,j] = sum_d relu(hi[i,d]+hj[j,d]) * w2[d]
// S = sigmoid(z + be2), diag 0. hibjb[1024][1024]: cols 0:512 hi, 512:1024 hj.
// f64 accumulation (closest to the top-k decision).
// ---------------------------------------------------------------------------
__global__ __launch_bounds__(256) void scores_v3(
    const float* __restrict__ hibjb, const float* __restrict__ We2,
    const float* __restrict__ be2, float* __restrict__ S)
{
    __shared__ float Hi[16][36];
    __shared__ float Hj[16][36];
    __shared__ float W2s[512];
    const int b = blockIdx.z;
    const int i0 = blockIdx.y * 32, j0 = blockIdx.x * 32;
    const int tid = threadIdx.x;
    const int tx = tid & 15, ty = tid >> 4;

    for (int t = tid; t < 512; t += 256) W2s[t] = We2[t];

    const int sr = tid >> 3, sc = (tid & 7) << 1;
    const float* hiptr = hibjb + (size_t)(b * 256 + i0 + sr) * 1024 + sc;
    const float* hjptr = hibjb + (size_t)(b * 256 + j0 + sr) * 1024 + 512 + sc;

    double a00 = 0.0, a01 = 0.0, a10 = 0.0, a11 = 0.0;
    for (int k0 = 0; k0 < 512; k0 += 16) {
        __syncthreads();
        float2 hv = *(const float2*)(hiptr + k0);
        float2 jv = *(const float2*)(hjptr + k0);
        Hi[sc + 0][sr] = hv.x; Hi[sc + 1][sr] = hv.y;
        Hj[sc + 0][sr] = jv.x; Hj[sc + 1][sr] = jv.y;
        __syncthreads();
        #pragma unroll
        for (int kk = 0; kk < 16; ++kk) {
            const double wv = (double)W2s[k0 + kk];
            const float hi0 = Hi[kk][ty * 2 + 0], hi1 = Hi[kk][ty * 2 + 1];
            const float hj0 = Hj[kk][tx * 2 + 0], hj1 = Hj[kk][tx * 2 + 1];
            a00 += (double)fmaxf(hi0 + hj0, 0.f) * wv;
            a01 += (double)fmaxf(hi0 + hj1, 0.f) * wv;
            a10 += (double)fmaxf(hi1 + hj0, 0.f) * wv;
            a11 += (double)fmaxf(hi1 + hj1, 0.f) * wv;
        }
    }
    const double bb = (double)be2[0];
    const int gi0 = i0 + ty * 2, gj0 = j0 + tx * 2;
    double zz[2][2] = {{a00, a01}, {a10, a11}};
    #pragma unroll
    for (int ii = 0; ii < 2; ++ii)
        #pragma unroll
        for (int jj = 0; jj < 2; ++jj) {
            double z = zz[ii][jj] + bb;
            float sc_ = (float)(1.0 / (1.0 + exp(-z)));
            if (gi0 + ii == gj0 + jj) sc_ = 0.f;
            S[(size_t)(b * 256 + gi0 + ii) * 256 + gj0 + jj] = sc_;
        }
}

// ---------------------------------------------------------------------------
// Top-k(25) one-hot per row of 256 (ties -> lower index, like lax.top_k).
// ---------------------------------------------------------------------------
__global__ __launch_bounds__(64) void topk_kernel(
    const float* __restrict__ S, float* __restrict__ out)
{
    const int row = blockIdx.x;
    const int lane = threadIdx.x;
    float v[4]; int sel[4] = {0, 0, 0, 0};
    #pragma unroll
    for (int t = 0; t < 4; ++t) v[t] = S[(size_t)row * 256 + t * 64 + lane];
    for (int it = 0; it < 25; ++it) {
        float bv = v[0]; int bi = lane;
        #pragma unroll
        for (int t = 1; t < 4; ++t) {
            int idx = t * 64 + lane;
            if (v[t] > bv) { bv = v[t]; bi = idx; }
        }
        #pragma unroll
        for (int off = 32; off; off >>= 1) {
            float ov = __shfl_xor(bv, off);
            int   oi = __shfl_xor(bi, off);
            if (ov > bv || (ov == bv && oi < bi)) { bv = ov; bi = oi; }
        }
        if ((bi & 63) == lane) { int t = bi >> 6; sel[t] = 1; v[t] = -INFINITY; }
    }
    #pragma unroll
    for (int t = 0; t < 4; ++t)
        out[(size_t)row * 256 + t * 64 + lane] = (float)sel[t];
}

// ---------------------------------------------------------------------------
extern "C" void kernel_launch(void* const* d_in, const int* in_sizes, int n_in,
                              void* d_out, int out_size, void* d_ws, size_t ws_size,
                              hipStream_t stream)
{
    const float* x      = (const float*)d_in[0];
    const float* Wqkv   = (const float*)d_in[2];
    const float* bqkv   = (const float*)d_in[3];
    const float* Wo     = (const float*)d_in[4];
    const float* bo     = (const float*)d_in[5];
    const float* Wp1    = (const float*)d_in[6];
    const float* bp1    = (const float*)d_in[7];
    const float* Wp2    = (const float*)d_in[8];
    const float* bp2    = (const float*)d_in[9];
    const float* Wfuse  = (const float*)d_in[10];
    const float* bfuse  = (const float*)d_in[11];
    const float* ln_g   = (const float*)d_in[12];
    const float* ln_b   = (const float*)d_in[13];
    const float* We1    = (const float*)d_in[14];
    const float* be1    = (const float*)d_in[15];
    const float* We2    = (const float*)d_in[16];
    const float* be2    = (const float*)d_in[17];
    const float* Ws_qkv = (const float*)d_in[18];
    const float* bs_qkv = (const float*)d_in[19];
    const float* Ws_o   = (const float*)d_in[20];
    const float* bs_o   = (const float*)d_in[21];

    float* out_att    = (float*)d_out;               // 4*256*512
    float* out_sparse = out_att + 4 * 256 * 512;     // 4*256*256

    // workspace layout (floats)
    float* ws    = (float*)d_ws;
    float* qkvb  = ws;                    // 1,572,864 (also y-buffer for fuse3)
    float* attnb = qkvb + 1572864;        //   524,288
    float* lvls  = attnb + 524288;        //   917,504 (lvl0 | lvl1 | lvl2)
    float* poolb = lvls + 917504;         //   131,072
    float* curb  = poolb + 131072;        //   262,144
    float* hier  = curb + 262144;         //   524,288
    float* hibjb = hier + 524288;         // 1,048,576  [1024][1024] (hi | hj)
    float* scb   = hibjb + 1048576;       //   262,144

    float* lvl0 = lvls;
    float* lvl1 = lvls + 1024 * 512;
    float* lvl2 = lvls + 1536 * 512;

    auto G32 = [&](const float* A, const float* W, const float* bias, float* C,
                   int M, int N, int K, int flags, int wmode) {
        gemm_v3<32, float><<<dim3(N / 64, M / 32), 256, 0, stream>>>(
            A, W, bias, C, M, N, K, flags, wmode);
    };

    // ---- Level 0 (n=256) ----
    G32(x, Wqkv, bqkv, qkvb, 1024, 1536, 512, 0, 0);
    attn_v2<4><<<dim3(16, 8, 4), 256, 0, stream>>>(qkvb, attnb, 256);
    G32(attnb, Wo, bo, lvl0, 1024, 512, 512, 0, 0);
    G32(lvl0, Wp1, bp1, poolb, 1024, 256, 512, 3, 0);     // relu+pool -> [512][256]
    G32(poolb, Wp2, bp2, curb, 512, 512, 256, 0, 0);

    // ---- Level 1 (n=128) ----
    G32(curb, Wqkv + 512 * 1536, bqkv + 1536, qkvb, 512, 1536, 512, 0, 0);
    attn_v2<2><<<dim3(8, 8, 4), 256, 0, stream>>>(qkvb, attnb, 128);
    G32(attnb, Wo + 512 * 512, bo + 512, lvl1, 512, 512, 512, 0, 0);
    G32(lvl1, Wp1 + 512 * 256, bp1 + 256, poolb, 512, 256, 512, 3, 0);  // -> [256][256]
    G32(poolb, Wp2 + 256 * 512, bp2 + 512, curb, 256, 512, 256, 0, 0);

    // ---- Level 2 (n=64) ----
    G32(curb, Wqkv + 2 * 512 * 1536, bqkv + 2 * 1536, qkvb, 256, 1536, 512, 0, 0);
    attn_v2<1><<<dim3(4, 8, 4), 256, 0, stream>>>(qkvb, attnb, 64);
    G32(attnb, Wo + 2 * 512 * 512, bo + 2 * 512, lvl2, 256, 512, 512, 0, 0);

    // ---- Fuse (batched partial GEMM) + LN ----
    G32(lvls, Wfuse, nullptr, qkvb, 1792, 512, 512, 0, 1);    // y -> qkvb
    ln3_kernel<<<1024, 64, 0, stream>>>(qkvb, bfuse, ln_g, ln_b, hier);

    // ---- Sparse edge scoring + top-k (scores dot stays f64) ----
    G32(hier, We1, be1, hibjb, 1024, 1024, 512, 0, 2);        // [hi | hj]
    scores_v3<<<dim3(8, 8, 4), 256, 0, stream>>>(hibjb, We2, be2, scb);
    topk_kernel<<<1024, 64, 0, stream>>>(scb, out_sparse);

    // ---- Final MHA on hier (feeds only output 0, bf16 tol) ----
    G32(hier, Ws_qkv, bs_qkv, qkvb, 1024, 1536, 512, 0, 0);
    attn_v2<4><<<dim3(16, 8, 4), 256, 0, stream>>>(qkvb, attnb, 256);
    G32(attnb, Ws_o, bs_o, out_att, 1024, 512, 512, 0, 0);
}

// Round 9
// 413.154 us; speedup vs baseline: 1.2069x; 1.0082x over previous
//
#include <hip/hip_runtime.h>
#include <math.h>

// Problem constants: B=4, N=256, D=512, H=8, HD=64, L=3, K_SPARSE=25, EPS=1e-5

// ---------------------------------------------------------------------------
// GEMM v3 (f32): C[M,N] = act(A[M,K] @ W[K,N] + bias). TM=32, thread owns
// 2 rows x 4 cols, vectorized LDS fragment reads.
// flags: 1 = relu, 2 = pool (pair-average rows, C gets M/2 rows)
// wmode: 0 none; 1 = fuse3 (W += seg(bm)*512*512, seg rows at 1024/1536);
//        2 = we1-split (W stride 512; bn>=512 -> W += 512*512, bias on; else no bias)
// ---------------------------------------------------------------------------
template <int TM, typename ACC>
__global__ __launch_bounds__(256) void gemm_v3(
    const float* __restrict__ A, const float* __restrict__ W,
    const float* __restrict__ bias, float* __restrict__ C,
    int M, int N, int K, int flags, int wmode)
{
    constexpr int RT = TM / 16;
    constexpr int PAD = 4;
    __shared__ ACC As[16][TM + PAD];
    __shared__ ACC Ws[16][64 + PAD];

    const int tid = threadIdx.x;
    const int tx = tid & 15, ty = tid >> 4;
    const int bm = blockIdx.y * TM, bn = blockIdx.x * 64;

    const float* Wp = W;
    const float* bp = bias;
    int wn = N, wcol = bn;
    if (wmode == 1) {
        int seg = (bm >= 1536) ? 2 : (bm >= 1024) ? 1 : 0;
        Wp += (size_t)seg * 262144;
    } else if (wmode == 2) {
        if (bn >= 512) Wp += 262144; else bp = nullptr;
        wn = 512; wcol = bn & 511;
    }

    const int ar = tid >> 3, ac = (tid & 7) << 1;
    const int wr = tid >> 4;
    const int wc = (tid & 15) << 2;

    const float* Aptr = A + (size_t)(bm + ar) * K + ac;
    const float* Wptr = Wp + (size_t)wr * wn + wcol + wc;

    ACC acc[RT][4] = {};
    float ra[2], rw[4];

    {   // initial prefetch (k0 = 0)
        float2 v = *(const float2*)Aptr; ra[0] = v.x; ra[1] = v.y;
        float4 w = *(const float4*)Wptr;
        rw[0]=w.x; rw[1]=w.y; rw[2]=w.z; rw[3]=w.w;
    }

    for (int k0 = 0; k0 < K; k0 += 16) {
        if (k0) __syncthreads();
        As[ac + 0][ar] = (ACC)ra[0];
        As[ac + 1][ar] = (ACC)ra[1];
        #pragma unroll
        for (int u = 0; u < 4; ++u) Ws[wr][wc + u] = (ACC)rw[u];
        __syncthreads();

        if (k0 + 16 < K) {
            float2 v = *(const float2*)(Aptr + k0 + 16); ra[0] = v.x; ra[1] = v.y;
            float4 w = *(const float4*)(Wptr + (size_t)(k0 + 16) * wn);
            rw[0]=w.x; rw[1]=w.y; rw[2]=w.z; rw[3]=w.w;
        }

        #pragma unroll
        for (int kk = 0; kk < 16; ++kk) {
            ACC a[RT], w[4];
            #pragma unroll
            for (int i = 0; i < RT; ++i) a[i] = As[kk][ty * RT + i];
            #pragma unroll
            for (int j = 0; j < 4; ++j) w[j] = Ws[kk][tx * 4 + j];
            #pragma unroll
            for (int i = 0; i < RT; ++i)
                #pragma unroll
                for (int j = 0; j < 4; ++j)
                    acc[i][j] += a[i] * w[j];
        }
    }

    #pragma unroll
    for (int j = 0; j < 4; ++j) {
        const int cn = bn + tx * 4 + j;
        const ACC bv = bp ? (ACC)bp[(wmode == 2) ? (cn & 511) : cn] : (ACC)0;
        if (flags & 2) {
            #pragma unroll
            for (int pi = 0; pi < RT / 2; ++pi) {
                ACC f0 = acc[2 * pi][j] + bv;
                ACC f1 = acc[2 * pi + 1][j] + bv;
                if (flags & 1) {
                    f0 = f0 > (ACC)0 ? f0 : (ACC)0;
                    f1 = f1 > (ACC)0 ? f1 : (ACC)0;
                }
                int prow = ((bm + ty * RT) >> 1) + pi;
                C[(size_t)prow * N + cn] = (float)((f0 + f1) * (ACC)0.5);
            }
        } else {
            #pragma unroll
            for (int i = 0; i < RT; ++i) {
                ACC f = acc[i][j] + bv;
                if (flags & 1) f = f > (ACC)0 ? f : (ACC)0;
                C[(size_t)(bm + ty * RT + i) * N + cn] = (float)f;
            }
        }
    }
}

// ---------------------------------------------------------------------------
// Fused MHA v2: out[b,i,h*64+d] = softmax(QK^T * 0.125) V
// qkv layout [B][n][1536] (q | k | v). Block = (16 q-rows, h, b), 4 waves;
// each wave owns 4 q-rows. NT = n/64 compile-time.
// ---------------------------------------------------------------------------
template <int NT>
__global__ __launch_bounds__(256) void attn_v2(
    const float* __restrict__ qkv, float* __restrict__ out, int n)
{
    const int lane = threadIdx.x & 63;
    const int w    = threadIdx.x >> 6;
    const int h = blockIdx.y, b = blockIdx.z;
    const int q0 = blockIdx.x * 16;
    const size_t base = (size_t)b * n * 1536;

    __shared__ float q_lds[16][64];
    __shared__ float kv_lds[64][65];
    __shared__ float p_lds[16][256];

    {   // load 16 q rows (1 float4 / thread)
        int r = threadIdx.x >> 4, c4 = (threadIdx.x & 15) << 2;
        float4 v = *(const float4*)(qkv + base + (size_t)(q0 + r) * 1536 + h * 64 + c4);
        q_lds[r][c4 + 0] = v.x; q_lds[r][c4 + 1] = v.y;
        q_lds[r][c4 + 2] = v.z; q_lds[r][c4 + 3] = v.w;
    }

    const int r0 = w * 4;
    const int sr = threadIdx.x >> 2;
    const int sq = threadIdx.x & 3;

    float s[4][NT];

    // ---- QK^T ----
    #pragma unroll
    for (int t = 0; t < NT; ++t) {
        const int j0 = t * 64;
        __syncthreads();
        {
            const float* src = qkv + base + (size_t)(j0 + sr) * 1536 + 512 + h * 64;
            #pragma unroll
            for (int u = 0; u < 4; ++u) {
                int c = u * 4 + sq;
                float4 v = *(const float4*)(src + c * 4);
                kv_lds[sr][c * 4 + 0] = v.x; kv_lds[sr][c * 4 + 1] = v.y;
                kv_lds[sr][c * 4 + 2] = v.z; kv_lds[sr][c * 4 + 3] = v.w;
            }
        }
        __syncthreads();
        float c0 = 0.f, c1 = 0.f, c2 = 0.f, c3 = 0.f;
        #pragma unroll
        for (int d = 0; d < 64; ++d) {
            const float kvv = kv_lds[lane][d];
            c0 = fmaf(q_lds[r0 + 0][d], kvv, c0);
            c1 = fmaf(q_lds[r0 + 1][d], kvv, c1);
            c2 = fmaf(q_lds[r0 + 2][d], kvv, c2);
            c3 = fmaf(q_lds[r0 + 3][d], kvv, c3);
        }
        s[0][t] = c0 * 0.125f; s[1][t] = c1 * 0.125f;
        s[2][t] = c2 * 0.125f; s[3][t] = c3 * 0.125f;
    }

    // ---- softmax per row ----
    double inv[4];
    #pragma unroll
    for (int qr = 0; qr < 4; ++qr) {
        float m = s[qr][0];
        #pragma unroll
        for (int t = 1; t < NT; ++t) m = fmaxf(m, s[qr][t]);
        #pragma unroll
        for (int off = 32; off; off >>= 1) m = fmaxf(m, __shfl_xor(m, off));
        double sum = 0.0;
        #pragma unroll
        for (int t = 0; t < NT; ++t) {
            float p = expf(s[qr][t] - m);
            p_lds[r0 + qr][t * 64 + lane] = p;
            sum += (double)p;
        }
        #pragma unroll
        for (int off = 32; off; off >>= 1) sum += __shfl_xor(sum, off);
        inv[qr] = 1.0 / sum;
    }

    // ---- PV (d = lane) ----
    float o0 = 0.f, o1 = 0.f, o2 = 0.f, o3 = 0.f;
    #pragma unroll
    for (int t = 0; t < NT; ++t) {
        const int j0 = t * 64;
        __syncthreads();
        {
            const float* src = qkv + base + (size_t)(j0 + sr) * 1536 + 1024 + h * 64;
            #pragma unroll
            for (int u = 0; u < 4; ++u) {
                int c = u * 4 + sq;
                float4 v = *(const float4*)(src + c * 4);
                kv_lds[sr][c * 4 + 0] = v.x; kv_lds[sr][c * 4 + 1] = v.y;
                kv_lds[sr][c * 4 + 2] = v.z; kv_lds[sr][c * 4 + 3] = v.w;
            }
        }
        __syncthreads();
        #pragma unroll
        for (int jl = 0; jl < 64; ++jl) {
            const float vv = kv_lds[jl][lane];
            o0 = fmaf(p_lds[r0 + 0][t * 64 + jl], vv, o0);
            o1 = fmaf(p_lds[r0 + 1][t * 64 + jl], vv, o1);
            o2 = fmaf(p_lds[r0 + 2][t * 64 + jl], vv, o2);
            o3 = fmaf(p_lds[r0 + 3][t * 64 + jl], vv, o3);
        }
    }
    const size_t obase = ((size_t)(b * n + q0 + r0)) * 512 + h * 64 + lane;
    out[obase + 0 * 512] = (float)((double)o0 * inv[0]);
    out[obase + 1 * 512] = (float)((double)o1 * inv[1]);
    out[obase + 2 * 512] = (float)((double)o2 * inv[2]);
    out[obase + 3 * 512] = (float)((double)o3 * inv[3]);
}

// ---------------------------------------------------------------------------
// Fused 3-way add + bias + relu + LayerNorm. y = [y0(1024r) | y1(512r) | y2(256r)]
// ---------------------------------------------------------------------------
__global__ __launch_bounds__(64) void ln3_kernel(
    const float* __restrict__ y, const float* __restrict__ bf,
    const float* __restrict__ g, const float* __restrict__ bta,
    float* __restrict__ out)
{
    const int r = blockIdx.x, lane = threadIdx.x;
    const int b = r >> 8, i = r & 255;
    const float* y0 = y + (size_t)r * 512;
    const float* y1 = y + (size_t)(1024 + b * 128 + (i >> 1)) * 512;
    const float* y2 = y + (size_t)(1536 + b * 64 + (i >> 2)) * 512;
    double v[8];
    double sum = 0.0;
    #pragma unroll
    for (int t = 0; t < 8; ++t) {
        int d = t * 64 + lane;
        double s = (double)y0[d] + (double)y1[d] + (double)y2[d] + (double)bf[d];
        s = s > 0.0 ? s : 0.0;
        v[t] = s; sum += s;
    }
    #pragma unroll
    for (int off = 32; off; off >>= 1) sum += __shfl_xor(sum, off);
    const double mean = sum * (1.0 / 512.0);
    double ss = 0.0;
    #pragma unroll
    for (int t = 0; t < 8; ++t) { double d = v[t] - mean; ss += d * d; }
    #pragma unroll
    for (int off = 32; off; off >>= 1) ss += __shfl_xor(ss, off);
    const double rstd = 1.0 / sqrt(ss * (1.0 / 512.0) + 1e-5);
    #pragma unroll
    for (int t = 0; t < 8; ++t) {
        int d = t * 64 + lane;
        out[(size_t)r * 512 + d] =
            (float)((v[t] - mean) * rstd * (double)g[d] + (double)bta[d]);
    }
}

// ---------------------------------------------------------------------------
// Edge scores v4: z[i,j] = sum_d relu(hi[i,d]+hj[j,d]) * w2[d]; f64 accum.
// 32x32 (i,j) tile per block, thread owns 2x2. 128-deep k-chunks in LDS
// ([d][34] layout, b64 fragment reads, conflict-free); We2 via scalar
// (wave-uniform) global loads -> zero vector-LDS traffic for w2.
// grid: (8 jt, 8 it, 4 b).
// ---------------------------------------------------------------------------
__global__ __launch_bounds__(256) void scores_v4(
    const float* __restrict__ hibjb, const float* __restrict__ We2,
    const float* __restrict__ be2, float* __restrict__ S)
{
    __shared__ float Hi[128][34];   // [d][i]
    __shared__ float Hj[128][34];   // [d][j]
    const int b = blockIdx.z;
    const int i0 = blockIdx.y * 32, j0 = blockIdx.x * 32;
    const int tid = threadIdx.x;
    const int tx = tid & 15, ty = tid >> 4;

    const int si = tid >> 3;          // staging row 0..31
    const int sd = (tid & 7) << 2;    // staging d-offset 0..28

    const float* hip = hibjb + (size_t)(b * 256 + i0 + si) * 1024 + sd;
    const float* hjp = hibjb + (size_t)(b * 256 + j0 + si) * 1024 + 512 + sd;

    double a00 = 0.0, a01 = 0.0, a10 = 0.0, a11 = 0.0;

    for (int k0 = 0; k0 < 512; k0 += 128) {
        __syncthreads();
        #pragma unroll
        for (int u = 0; u < 4; ++u) {
            const int dch = u * 32 + sd;
            float4 v = *(const float4*)(hip + k0 + u * 32);
            Hi[dch + 0][si] = v.x; Hi[dch + 1][si] = v.y;
            Hi[dch + 2][si] = v.z; Hi[dch + 3][si] = v.w;
            float4 w = *(const float4*)(hjp + k0 + u * 32);
            Hj[dch + 0][si] = w.x; Hj[dch + 1][si] = w.y;
            Hj[dch + 2][si] = w.z; Hj[dch + 3][si] = w.w;
        }
        __syncthreads();
        #pragma unroll 16
        for (int kk = 0; kk < 128; ++kk) {
            const double wv = (double)We2[k0 + kk];   // wave-uniform -> s_load
            const float2 hi = *(const float2*)&Hi[kk][ty * 2];
            const float2 hj = *(const float2*)&Hj[kk][tx * 2];
            a00 += (double)fmaxf(hi.x + hj.x, 0.f) * wv;
            a01 += (double)fmaxf(hi.x + hj.y, 0.f) * wv;
            a10 += (double)fmaxf(hi.y + hj.x, 0.f) * wv;
            a11 += (double)fmaxf(hi.y + hj.y, 0.f) * wv;
        }
    }

    const double bb = (double)be2[0];
    const int gi0 = i0 + ty * 2, gj0 = j0 + tx * 2;
    double zz[2][2] = {{a00, a01}, {a10, a11}};
    #pragma unroll
    for (int ii = 0; ii < 2; ++ii)
        #pragma unroll
        for (int jj = 0; jj < 2; ++jj) {
            double z = zz[ii][jj] + bb;
            float sc_ = (float)(1.0 / (1.0 + exp(-z)));
            if (gi0 + ii == gj0 + jj) sc_ = 0.f;
            S[(size_t)(b * 256 + gi0 + ii) * 256 + gj0 + jj] = sc_;
        }
}

// ---------------------------------------------------------------------------
// Top-k(25) one-hot per row of 256 (ties -> lower index, like lax.top_k).
// ---------------------------------------------------------------------------
__global__ __launch_bounds__(64) void topk_kernel(
    const float* __restrict__ S, float* __restrict__ out)
{
    const int row = blockIdx.x;
    const int lane = threadIdx.x;
    float v[4]; int sel[4] = {0, 0, 0, 0};
    #pragma unroll
    for (int t = 0; t < 4; ++t) v[t] = S[(size_t)row * 256 + t * 64 + lane];
    for (int it = 0; it < 25; ++it) {
        float bv = v[0]; int bi = lane;
        #pragma unroll
        for (int t = 1; t < 4; ++t) {
            int idx = t * 64 + lane;
            if (v[t] > bv) { bv = v[t]; bi = idx; }
        }
        #pragma unroll
        for (int off = 32; off; off >>= 1) {
            float ov = __shfl_xor(bv, off);
            int   oi = __shfl_xor(bi, off);
            if (ov > bv || (ov == bv && oi < bi)) { bv = ov; bi = oi; }
        }
        if ((bi & 63) == lane) { int t = bi >> 6; sel[t] = 1; v[t] = -INFINITY; }
    }
    #pragma unroll
    for (int t = 0; t < 4; ++t)
        out[(size_t)row * 256 + t * 64 + lane] = (float)sel[t];
}

// ---------------------------------------------------------------------------
extern "C" void kernel_launch(void* const* d_in, const int* in_sizes, int n_in,
                              void* d_out, int out_size, void* d_ws, size_t ws_size,
                              hipStream_t stream)
{
    const float* x      = (const float*)d_in[0];
    const float* Wqkv   = (const float*)d_in[2];
    const float* bqkv   = (const float*)d_in[3];
    const float* Wo     = (const float*)d_in[4];
    const float* bo     = (const float*)d_in[5];
    const float* Wp1    = (const float*)d_in[6];
    const float* bp1    = (const float*)d_in[7];
    const float* Wp2    = (const float*)d_in[8];
    const float* bp2    = (const float*)d_in[9];
    const float* Wfuse  = (const float*)d_in[10];
    const float* bfuse  = (const float*)d_in[11];
    const float* ln_g   = (const float*)d_in[12];
    const float* ln_b   = (const float*)d_in[13];
    const float* We1    = (const float*)d_in[14];
    const float* be1    = (const float*)d_in[15];
    const float* We2    = (const float*)d_in[16];
    const float* be2    = (const float*)d_in[17];
    const float* Ws_qkv = (const float*)d_in[18];
    const float* bs_qkv = (const float*)d_in[19];
    const float* Ws_o   = (const float*)d_in[20];
    const float* bs_o   = (const float*)d_in[21];

    float* out_att    = (float*)d_out;               // 4*256*512
    float* out_sparse = out_att + 4 * 256 * 512;     // 4*256*256

    // workspace layout (floats)
    float* ws    = (float*)d_ws;
    float* qkvb  = ws;                    // 1,572,864 (also y-buffer for fuse3)
    float* attnb = qkvb + 1572864;        //   524,288
    float* lvls  = attnb + 524288;        //   917,504 (lvl0 | lvl1 | lvl2)
    float* poolb = lvls + 917504;         //   131,072
    float* curb  = poolb + 131072;        //   262,144
    float* hier  = curb + 262144;         //   524,288
    float* hibjb = hier + 524288;         // 1,048,576  [1024][1024] (hi | hj)
    float* scb   = hibjb + 1048576;       //   262,144

    float* lvl0 = lvls;
    float* lvl1 = lvls + 1024 * 512;
    float* lvl2 = lvls + 1536 * 512;

    auto G32 = [&](const float* A, const float* W, const float* bias, float* C,
                   int M, int N, int K, int flags, int wmode) {
        gemm_v3<32, float><<<dim3(N / 64, M / 32), 256, 0, stream>>>(
            A, W, bias, C, M, N, K, flags, wmode);
    };

    // ---- Level 0 (n=256) ----
    G32(x, Wqkv, bqkv, qkvb, 1024, 1536, 512, 0, 0);
    attn_v2<4><<<dim3(16, 8, 4), 256, 0, stream>>>(qkvb, attnb, 256);
    G32(attnb, Wo, bo, lvl0, 1024, 512, 512, 0, 0);
    G32(lvl0, Wp1, bp1, poolb, 1024, 256, 512, 3, 0);     // relu+pool -> [512][256]
    G32(poolb, Wp2, bp2, curb, 512, 512, 256, 0, 0);

    // ---- Level 1 (n=128) ----
    G32(curb, Wqkv + 512 * 1536, bqkv + 1536, qkvb, 512, 1536, 512, 0, 0);
    attn_v2<2><<<dim3(8, 8, 4), 256, 0, stream>>>(qkvb, attnb, 128);
    G32(attnb, Wo + 512 * 512, bo + 512, lvl1, 512, 512, 512, 0, 0);
    G32(lvl1, Wp1 + 512 * 256, bp1 + 256, poolb, 512, 256, 512, 3, 0);  // -> [256][256]
    G32(poolb, Wp2 + 256 * 512, bp2 + 512, curb, 256, 512, 256, 0, 0);

    // ---- Level 2 (n=64) ----
    G32(curb, Wqkv + 2 * 512 * 1536, bqkv + 2 * 1536, qkvb, 256, 1536, 512, 0, 0);
    attn_v2<1><<<dim3(4, 8, 4), 256, 0, stream>>>(qkvb, attnb, 64);
    G32(attnb, Wo + 2 * 512 * 512, bo + 2 * 512, lvl2, 256, 512, 512, 0, 0);

    // ---- Fuse (batched partial GEMM) + LN ----
    G32(lvls, Wfuse, nullptr, qkvb, 1792, 512, 512, 0, 1);    // y -> qkvb
    ln3_kernel<<<1024, 64, 0, stream>>>(qkvb, bfuse, ln_g, ln_b, hier);

    // ---- Sparse edge scoring + top-k (scores dot stays f64) ----
    G32(hier, We1, be1, hibjb, 1024, 1024, 512, 0, 2);        // [hi | hj]
    scores_v4<<<dim3(8, 8, 4), 256, 0, stream>>>(hibjb, We2, be2, scb);
    topk_kernel<<<1024, 64, 0, stream>>>(scb, out_sparse);

    // ---- Final MHA on hier (feeds only output 0, bf16 tol) ----
    G32(hier, Ws_qkv, bs_qkv, qkvb, 1024, 1536, 512, 0, 0);
    attn_v2<4><<<dim3(16, 8, 4), 256, 0, stream>>>(qkvb, attnb, 256);
    G32(attnb, Ws_o, bs_o, out_att, 1024, 512, 512, 0, 0);
}

// Round 10
// 391.062 us; speedup vs baseline: 1.2751x; 1.0565x over previous
//
#include <hip/hip_runtime.h>
#include <math.h>

// Problem constants: B=4, N=256, D=512, H=8, HD=64, L=3, K_SPARSE=25, EPS=1e-5

// ---------------------------------------------------------------------------
// GEMM v4 (f32): C[M,N] = act(A[M,K] @ W[K,N] + bias).
// TM=64: thread owns 4 consecutive rows x 4 cols -> b128 A-read (broadcast)
//        + b128 W-read (2-way, free) per 16 FMAs  => FMA-bound.
// TM=32: thread owns 2 rows x 4 cols (for small-M GEMMs needing more blocks).
// flags: 1 = relu, 2 = pool (pair-average rows, C gets M/2 rows)
// wmode: 0 none
//        1 = fuse3 (W += seg(bm)*512*512, seg rows at 1024/1536; wn=N=512)
//        3 = hier-merged: cols [0,1536) = W (Ws_qkv, wn=1536, bias),
//            [1536,2048) = W2 rows 0-511 (no bias), [2048,2560) = W2+512*512
//            rows (bias2). N (=2560) is the C row stride.
// ---------------------------------------------------------------------------
template <int TM>
__global__ __launch_bounds__(256) void gemm_v4(
    const float* __restrict__ A, const float* __restrict__ W,
    const float* __restrict__ bias, float* __restrict__ C,
    int M, int N, int K, int flags, int wmode,
    const float* __restrict__ W2, const float* __restrict__ bias2)
{
    constexpr int RT = TM / 16;
    __shared__ float As[16][TM + 4];
    __shared__ float Ws[16][68];

    const int tid = threadIdx.x;
    const int tx = tid & 15, ty = tid >> 4;
    const int bm = blockIdx.y * TM, bn = blockIdx.x * 64;

    const float* Wp = W;
    const float* bp = bias;
    int wn = N, wcol = bn;
    if (wmode == 1) {
        int seg = (bm >= 1536) ? 2 : (bm >= 1024) ? 1 : 0;
        Wp += (size_t)seg * 262144;
    } else if (wmode == 3) {
        if (bn < 1536)      { wn = 1536; wcol = bn; }
        else if (bn < 2048) { Wp = W2;           wn = 512; wcol = bn - 1536; bp = nullptr; }
        else                { Wp = W2 + 262144;  wn = 512; wcol = bn - 2048; bp = bias2; }
    }

    // staging maps
    constexpr int AV = (TM == 64) ? 4 : 2;
    const int ar = (TM == 64) ? (tid >> 2) : (tid >> 3);
    const int ac = (TM == 64) ? ((tid & 3) << 2) : ((tid & 7) << 1);
    const int wr = tid >> 4;
    const int wc = (tid & 15) << 2;

    const float* Aptr = A + (size_t)(bm + ar) * K + ac;
    const float* Wptr = Wp + (size_t)wr * wn + wcol + wc;

    float acc[RT][4] = {};
    float ra[AV], rw[4];

    {   // initial prefetch (k0 = 0)
        if (TM == 64) { float4 v = *(const float4*)Aptr;
            ra[0]=v.x; ra[1]=v.y; ra[2]=v.z; ra[3]=v.w; }
        else { float2 v = *(const float2*)Aptr; ra[0]=v.x; ra[1]=v.y; }
        float4 w = *(const float4*)Wptr;
        rw[0]=w.x; rw[1]=w.y; rw[2]=w.z; rw[3]=w.w;
    }

    for (int k0 = 0; k0 < K; k0 += 16) {
        if (k0) __syncthreads();
        #pragma unroll
        for (int u = 0; u < AV; ++u) As[ac + u][ar] = ra[u];
        #pragma unroll
        for (int u = 0; u < 4; ++u) Ws[wr][wc + u] = rw[u];
        __syncthreads();

        if (k0 + 16 < K) {
            const float* ap = Aptr + k0 + 16;
            if (TM == 64) { float4 v = *(const float4*)ap;
                ra[0]=v.x; ra[1]=v.y; ra[2]=v.z; ra[3]=v.w; }
            else { float2 v = *(const float2*)ap; ra[0]=v.x; ra[1]=v.y; }
            float4 w = *(const float4*)(Wptr + (size_t)(k0 + 16) * wn);
            rw[0]=w.x; rw[1]=w.y; rw[2]=w.z; rw[3]=w.w;
        }

        #pragma unroll
        for (int kk = 0; kk < 16; ++kk) {
            float a[RT];
            if constexpr (RT == 4) {
                float4 t = *(const float4*)&As[kk][ty * 4];
                a[0]=t.x; a[1]=t.y; a[2]=t.z; a[3]=t.w;
            } else {
                float2 t = *(const float2*)&As[kk][ty * 2];
                a[0]=t.x; a[1]=t.y;
            }
            float4 tw = *(const float4*)&Ws[kk][tx * 4];
            float w[4] = {tw.x, tw.y, tw.z, tw.w};
            #pragma unroll
            for (int i = 0; i < RT; ++i)
                #pragma unroll
                for (int j = 0; j < 4; ++j)
                    acc[i][j] = fmaf(a[i], w[j], acc[i][j]);
        }
    }

    // epilogue
    #pragma unroll
    for (int j = 0; j < 4; ++j) {
        const int cn = bn + tx * 4 + j;
        const float bv = bp ? bp[wcol + tx * 4 + j] : 0.f;
        if (flags & 2) {   // pool: pair-average activated rows
            #pragma unroll
            for (int pi = 0; pi < RT / 2; ++pi) {
                float f0 = acc[2 * pi][j] + bv;
                float f1 = acc[2 * pi + 1][j] + bv;
                if (flags & 1) { f0 = fmaxf(f0, 0.f); f1 = fmaxf(f1, 0.f); }
                int prow = ((bm + ty * RT) >> 1) + pi;
                C[(size_t)prow * N + cn] = (f0 + f1) * 0.5f;
            }
        } else {
            #pragma unroll
            for (int i = 0; i < RT; ++i) {
                float f = acc[i][j] + bv;
                if (flags & 1) f = fmaxf(f, 0.f);
                C[(size_t)(bm + ty * RT + i) * N + cn] = f;
            }
        }
    }
}

// ---------------------------------------------------------------------------
// Fused MHA v2: out[b,i,h*64+d] = softmax(QK^T * 0.125) V
// qkv rows of length qstride with q|k|v at offsets 0/512/1024.
// Block = (16 q-rows, h, b), 4 waves; each wave owns 4 q-rows. NT = n/64.
// ---------------------------------------------------------------------------
template <int NT>
__global__ __launch_bounds__(256) void attn_v2(
    const float* __restrict__ qkv, float* __restrict__ out, int n, int qstride)
{
    const int lane = threadIdx.x & 63;
    const int w    = threadIdx.x >> 6;
    const int h = blockIdx.y, b = blockIdx.z;
    const int q0 = blockIdx.x * 16;
    const size_t base = (size_t)b * n * qstride;

    __shared__ float q_lds[16][64];
    __shared__ float kv_lds[64][65];
    __shared__ float p_lds[16][256];

    {   // load 16 q rows (1 float4 / thread)
        int r = threadIdx.x >> 4, c4 = (threadIdx.x & 15) << 2;
        float4 v = *(const float4*)(qkv + base + (size_t)(q0 + r) * qstride + h * 64 + c4);
        q_lds[r][c4 + 0] = v.x; q_lds[r][c4 + 1] = v.y;
        q_lds[r][c4 + 2] = v.z; q_lds[r][c4 + 3] = v.w;
    }

    const int r0 = w * 4;
    const int sr = threadIdx.x >> 2;
    const int sq = threadIdx.x & 3;

    float s[4][NT];

    // ---- QK^T ----
    #pragma unroll
    for (int t = 0; t < NT; ++t) {
        const int j0 = t * 64;
        __syncthreads();
        {
            const float* src = qkv + base + (size_t)(j0 + sr) * qstride + 512 + h * 64;
            #pragma unroll
            for (int u = 0; u < 4; ++u) {
                int c = u * 4 + sq;
                float4 v = *(const float4*)(src + c * 4);
                kv_lds[sr][c * 4 + 0] = v.x; kv_lds[sr][c * 4 + 1] = v.y;
                kv_lds[sr][c * 4 + 2] = v.z; kv_lds[sr][c * 4 + 3] = v.w;
            }
        }
        __syncthreads();
        float c0 = 0.f, c1 = 0.f, c2 = 0.f, c3 = 0.f;
        #pragma unroll
        for (int d = 0; d < 64; ++d) {
            const float kvv = kv_lds[lane][d];
            c0 = fmaf(q_lds[r0 + 0][d], kvv, c0);
            c1 = fmaf(q_lds[r0 + 1][d], kvv, c1);
            c2 = fmaf(q_lds[r0 + 2][d], kvv, c2);
            c3 = fmaf(q_lds[r0 + 3][d], kvv, c3);
        }
        s[0][t] = c0 * 0.125f; s[1][t] = c1 * 0.125f;
        s[2][t] = c2 * 0.125f; s[3][t] = c3 * 0.125f;
    }

    // ---- softmax per row ----
    double inv[4];
    #pragma unroll
    for (int qr = 0; qr < 4; ++qr) {
        float m = s[qr][0];
        #pragma unroll
        for (int t = 1; t < NT; ++t) m = fmaxf(m, s[qr][t]);
        #pragma unroll
        for (int off = 32; off; off >>= 1) m = fmaxf(m, __shfl_xor(m, off));
        double sum = 0.0;
        #pragma unroll
        for (int t = 0; t < NT; ++t) {
            float p = expf(s[qr][t] - m);
            p_lds[r0 + qr][t * 64 + lane] = p;
            sum += (double)p;
        }
        #pragma unroll
        for (int off = 32; off; off >>= 1) sum += __shfl_xor(sum, off);
        inv[qr] = 1.0 / sum;
    }

    // ---- PV (d = lane) ----
    float o0 = 0.f, o1 = 0.f, o2 = 0.f, o3 = 0.f;
    #pragma unroll
    for (int t = 0; t < NT; ++t) {
        const int j0 = t * 64;
        __syncthreads();
        {
            const float* src = qkv + base + (size_t)(j0 + sr) * qstride + 1024 + h * 64;
            #pragma unroll
            for (int u = 0; u < 4; ++u) {
                int c = u * 4 + sq;
                float4 v = *(const float4*)(src + c * 4);
                kv_lds[sr][c * 4 + 0] = v.x; kv_lds[sr][c * 4 + 1] = v.y;
                kv_lds[sr][c * 4 + 2] = v.z; kv_lds[sr][c * 4 + 3] = v.w;
            }
        }
        __syncthreads();
        #pragma unroll
        for (int jl = 0; jl < 64; ++jl) {
            const float vv = kv_lds[jl][lane];
            o0 = fmaf(p_lds[r0 + 0][t * 64 + jl], vv, o0);
            o1 = fmaf(p_lds[r0 + 1][t * 64 + jl], vv, o1);
            o2 = fmaf(p_lds[r0 + 2][t * 64 + jl], vv, o2);
            o3 = fmaf(p_lds[r0 + 3][t * 64 + jl], vv, o3);
        }
    }
    const size_t obase = ((size_t)(b * n + q0 + r0)) * 512 + h * 64 + lane;
    out[obase + 0 * 512] = (float)((double)o0 * inv[0]);
    out[obase + 1 * 512] = (float)((double)o1 * inv[1]);
    out[obase + 2 * 512] = (float)((double)o2 * inv[2]);
    out[obase + 3 * 512] = (float)((double)o3 * inv[3]);
}

// ---------------------------------------------------------------------------
// Fused 3-way add + bias + relu + LayerNorm. y = [y0(1024r) | y1(512r) | y2(256r)]
// ---------------------------------------------------------------------------
__global__ __launch_bounds__(64) void ln3_kernel(
    const float* __restrict__ y, const float* __restrict__ bf,
    const float* __restrict__ g, const float* __restrict__ bta,
    float* __restrict__ out)
{
    const int r = blockIdx.x, lane = threadIdx.x;
    const int b = r >> 8, i = r & 255;
    const float* y0 = y + (size_t)r * 512;
    const float* y1 = y + (size_t)(1024 + b * 128 + (i >> 1)) * 512;
    const float* y2 = y + (size_t)(1536 + b * 64 + (i >> 2)) * 512;
    double v[8];
    double sum = 0.0;
    #pragma unroll
    for (int t = 0; t < 8; ++t) {
        int d = t * 64 + lane;
        double s = (double)y0[d] + (double)y1[d] + (double)y2[d] + (double)bf[d];
        s = s > 0.0 ? s : 0.0;
        v[t] = s; sum += s;
    }
    #pragma unroll
    for (int off = 32; off; off >>= 1) sum += __shfl_xor(sum, off);
    const double mean = sum * (1.0 / 512.0);
    double ss = 0.0;
    #pragma unroll
    for (int t = 0; t < 8; ++t) { double d = v[t] - mean; ss += d * d; }
    #pragma unroll
    for (int off = 32; off; off >>= 1) ss += __shfl_xor(ss, off);
    const double rstd = 1.0 / sqrt(ss * (1.0 / 512.0) + 1e-5);
    #pragma unroll
    for (int t = 0; t < 8; ++t) {
        int d = t * 64 + lane;
        out[(size_t)r * 512 + d] =
            (float)((v[t] - mean) * rstd * (double)g[d] + (double)bta[d]);
    }
}

// ---------------------------------------------------------------------------
// Edge scores v4: z[i,j] = sum_d relu(hi[i,d]+hj[j,d]) * w2[d]; f64 accum.
// hq rows of length `stride`; hi at col `off`, hj at `off+512`.
// 32x32 (i,j) tile per block, thread owns 2x2. 128-deep k-chunks in LDS;
// We2 via wave-uniform scalar loads. grid: (8 jt, 8 it, 4 b).
// ---------------------------------------------------------------------------
__global__ __launch_bounds__(256) void scores_v4(
    const float* __restrict__ hq, int stride, int off,
    const float* __restrict__ We2, const float* __restrict__ be2,
    float* __restrict__ S)
{
    __shared__ float Hi[128][34];   // [d][i]
    __shared__ float Hj[128][34];   // [d][j]
    const int b = blockIdx.z;
    const int i0 = blockIdx.y * 32, j0 = blockIdx.x * 32;
    const int tid = threadIdx.x;
    const int tx = tid & 15, ty = tid >> 4;

    const int si = tid >> 3;          // staging row 0..31
    const int sd = (tid & 7) << 2;    // staging d-offset 0..28

    const float* hip = hq + (size_t)(b * 256 + i0 + si) * stride + off + sd;
    const float* hjp = hq + (size_t)(b * 256 + j0 + si) * stride + off + 512 + sd;

    double a00 = 0.0, a01 = 0.0, a10 = 0.0, a11 = 0.0;

    for (int k0 = 0; k0 < 512; k0 += 128) {
        __syncthreads();
        #pragma unroll
        for (int u = 0; u < 4; ++u) {
            const int dch = u * 32 + sd;
            float4 v = *(const float4*)(hip + k0 + u * 32);
            Hi[dch + 0][si] = v.x; Hi[dch + 1][si] = v.y;
            Hi[dch + 2][si] = v.z; Hi[dch + 3][si] = v.w;
            float4 w = *(const float4*)(hjp + k0 + u * 32);
            Hj[dch + 0][si] = w.x; Hj[dch + 1][si] = w.y;
            Hj[dch + 2][si] = w.z; Hj[dch + 3][si] = w.w;
        }
        __syncthreads();
        #pragma unroll 16
        for (int kk = 0; kk < 128; ++kk) {
            const double wv = (double)We2[k0 + kk];   // wave-uniform -> s_load
            const float2 hi = *(const float2*)&Hi[kk][ty * 2];
            const float2 hj = *(const float2*)&Hj[kk][tx * 2];
            a00 += (double)fmaxf(hi.x + hj.x, 0.f) * wv;
            a01 += (double)fmaxf(hi.x + hj.y, 0.f) * wv;
            a10 += (double)fmaxf(hi.y + hj.x, 0.f) * wv;
            a11 += (double)fmaxf(hi.y + hj.y, 0.f) * wv;
        }
    }

    const double bb = (double)be2[0];
    const int gi0 = i0 + ty * 2, gj0 = j0 + tx * 2;
    double zz[2][2] = {{a00, a01}, {a10, a11}};
    #pragma unroll
    for (int ii = 0; ii < 2; ++ii)
        #pragma unroll
        for (int jj = 0; jj < 2; ++jj) {
            double z = zz[ii][jj] + bb;
            float sc_ = (float)(1.0 / (1.0 + exp(-z)));
            if (gi0 + ii == gj0 + jj) sc_ = 0.f;
            S[(size_t)(b * 256 + gi0 + ii) * 256 + gj0 + jj] = sc_;
        }
}

// ---------------------------------------------------------------------------
// Top-k(25) one-hot per row of 256 (ties -> lower index, like lax.top_k).
// ---------------------------------------------------------------------------
__global__ __launch_bounds__(64) void topk_kernel(
    const float* __restrict__ S, float* __restrict__ out)
{
    const int row = blockIdx.x;
    const int lane = threadIdx.x;
    float v[4]; int sel[4] = {0, 0, 0, 0};
    #pragma unroll
    for (int t = 0; t < 4; ++t) v[t] = S[(size_t)row * 256 + t * 64 + lane];
    for (int it = 0; it < 25; ++it) {
        float bv = v[0]; int bi = lane;
        #pragma unroll
        for (int t = 1; t < 4; ++t) {
            int idx = t * 64 + lane;
            if (v[t] > bv) { bv = v[t]; bi = idx; }
        }
        #pragma unroll
        for (int off = 32; off; off >>= 1) {
            float ov = __shfl_xor(bv, off);
            int   oi = __shfl_xor(bi, off);
            if (ov > bv || (ov == bv && oi < bi)) { bv = ov; bi = oi; }
        }
        if ((bi & 63) == lane) { int t = bi >> 6; sel[t] = 1; v[t] = -INFINITY; }
    }
    #pragma unroll
    for (int t = 0; t < 4; ++t)
        out[(size_t)row * 256 + t * 64 + lane] = (float)sel[t];
}

// ---------------------------------------------------------------------------
extern "C" void kernel_launch(void* const* d_in, const int* in_sizes, int n_in,
                              void* d_out, int out_size, void* d_ws, size_t ws_size,
                              hipStream_t stream)
{
    const float* x      = (const float*)d_in[0];
    const float* Wqkv   = (const float*)d_in[2];
    const float* bqkv   = (const float*)d_in[3];
    const float* Wo     = (const float*)d_in[4];
    const float* bo     = (const float*)d_in[5];
    const float* Wp1    = (const float*)d_in[6];
    const float* bp1    = (const float*)d_in[7];
    const float* Wp2    = (const float*)d_in[8];
    const float* bp2    = (const float*)d_in[9];
    const float* Wfuse  = (const float*)d_in[10];
    const float* bfuse  = (const float*)d_in[11];
    const float* ln_g   = (const float*)d_in[12];
    const float* ln_b   = (const float*)d_in[13];
    const float* We1    = (const float*)d_in[14];
    const float* be1    = (const float*)d_in[15];
    const float* We2    = (const float*)d_in[16];
    const float* be2    = (const float*)d_in[17];
    const float* Ws_qkv = (const float*)d_in[18];
    const float* bs_qkv = (const float*)d_in[19];
    const float* Ws_o   = (const float*)d_in[20];
    const float* bs_o   = (const float*)d_in[21];

    float* out_att    = (float*)d_out;               // 4*256*512
    float* out_sparse = out_att + 4 * 256 * 512;     // 4*256*256

    // workspace layout (floats)
    float* ws    = (float*)d_ws;
    float* qkvb  = ws;                    // 1,572,864 (also y-buffer for fuse3)
    float* attnb = qkvb + 1572864;        //   524,288
    float* lvls  = attnb + 524288;        //   917,504 (lvl0 | lvl1 | lvl2)
    float* poolb = lvls + 917504;         //   131,072
    float* curb  = poolb + 131072;        //   262,144
    float* hier  = curb + 262144;         //   524,288
    float* scb   = hier + 524288;         //   262,144
    float* qh    = scb + 262144;          // 2,621,440  [1024][2560] (qkv|hi|hj)

    float* lvl0 = lvls;
    float* lvl1 = lvls + 1024 * 512;
    float* lvl2 = lvls + 1536 * 512;

    auto G64 = [&](const float* A, const float* W, const float* bias, float* C,
                   int M, int N, int K, int flags, int wmode,
                   const float* W2 = nullptr, const float* bias2 = nullptr) {
        gemm_v4<64><<<dim3(N / 64, M / 64), 256, 0, stream>>>(
            A, W, bias, C, M, N, K, flags, wmode, W2, bias2);
    };
    auto G32 = [&](const float* A, const float* W, const float* bias, float* C,
                   int M, int N, int K, int flags, int wmode) {
        gemm_v4<32><<<dim3(N / 64, M / 32), 256, 0, stream>>>(
            A, W, bias, C, M, N, K, flags, wmode, nullptr, nullptr);
    };

    // ---- Level 0 (n=256) ----
    G64(x, Wqkv, bqkv, qkvb, 1024, 1536, 512, 0, 0);
    attn_v2<4><<<dim3(16, 8, 4), 256, 0, stream>>>(qkvb, attnb, 256, 1536);
    G32(attnb, Wo, bo, lvl0, 1024, 512, 512, 0, 0);
    G32(lvl0, Wp1, bp1, poolb, 1024, 256, 512, 3, 0);     // relu+pool -> [512][256]
    G32(poolb, Wp2, bp2, curb, 512, 512, 256, 0, 0);

    // ---- Level 1 (n=128) ----
    G64(curb, Wqkv + 512 * 1536, bqkv + 1536, qkvb, 512, 1536, 512, 0, 0);
    attn_v2<2><<<dim3(8, 8, 4), 256, 0, stream>>>(qkvb, attnb, 128, 1536);
    G32(attnb, Wo + 512 * 512, bo + 512, lvl1, 512, 512, 512, 0, 0);
    G32(lvl1, Wp1 + 512 * 256, bp1 + 256, poolb, 512, 256, 512, 3, 0);  // -> [256][256]
    G32(poolb, Wp2 + 256 * 512, bp2 + 512, curb, 256, 512, 256, 0, 0);

    // ---- Level 2 (n=64) ----
    G32(curb, Wqkv + 2 * 512 * 1536, bqkv + 2 * 1536, qkvb, 256, 1536, 512, 0, 0);
    attn_v2<1><<<dim3(4, 8, 4), 256, 0, stream>>>(qkvb, attnb, 64, 1536);
    G32(attnb, Wo + 2 * 512 * 512, bo + 2 * 512, lvl2, 256, 512, 512, 0, 0);

    // ---- Fuse (batched partial GEMM) + LN ----
    G64(lvls, Wfuse, nullptr, qkvb, 1792, 512, 512, 0, 1);    // y -> qkvb
    ln3_kernel<<<1024, 64, 0, stream>>>(qkvb, bfuse, ln_g, ln_b, hier);

    // ---- Merged hier GEMM: [final qkv | hi | hj] in one dispatch ----
    G64(hier, Ws_qkv, bs_qkv, qh, 1024, 2560, 512, 0, 3, We1, be1);

    // ---- Sparse edge scoring + top-k (scores dot stays f64) ----
    scores_v4<<<dim3(8, 8, 4), 256, 0, stream>>>(qh, 2560, 1536, We2, be2, scb);
    topk_kernel<<<1024, 64, 0, stream>>>(scb, out_sparse);

    // ---- Final MHA on hier (feeds only output 0, bf16 tol) ----
    attn_v2<4><<<dim3(16, 8, 4), 256, 0, stream>>>(qh, attnb, 256, 2560);
    G32(attnb, Ws_o, bs_o, out_att, 1024, 512, 512, 0, 0);
}